// Round 1
// baseline (465.884 us; speedup 1.0000x reference)
//
#include <hip/hip_runtime.h>
#include <math.h>

#define F_IN 256
#define HDIM 128
#define NCLS 20
#define NEG_SLOPE 0.2f

static __device__ __forceinline__ float lrelu(float x) { return x > 0.f ? x : NEG_SLOPE * x; }

// ---------------- CSR build ----------------
__global__ void count_kernel(const int* __restrict__ ei, int E, int N, int* __restrict__ deg) {
    int e = blockIdx.x * blockDim.x + threadIdx.x;
    int Etot = E + N;
    if (e >= Etot) return;
    int d = (e < E) ? ei[E + e] : (e - E);
    atomicAdd(&deg[d], 1);
}

__global__ __launch_bounds__(1024) void scan_kernel(const int* __restrict__ deg, int* __restrict__ off, int n) {
    __shared__ int sums[1024];
    int tid = threadIdx.x;
    int chunk = (n + 1023) / 1024;
    int start = tid * chunk; if (start > n) start = n;
    int end = start + chunk; if (end > n) end = n;
    int s = 0;
    for (int i = start; i < end; ++i) s += deg[i];
    sums[tid] = s;
    __syncthreads();
    for (int d = 1; d < 1024; d <<= 1) {
        int v = (tid >= d) ? sums[tid - d] : 0;
        __syncthreads();
        sums[tid] += v;
        __syncthreads();
    }
    int prefix = (tid == 0) ? 0 : sums[tid - 1];
    for (int i = start; i < end; ++i) { off[i] = prefix; prefix += deg[i]; }
    if (tid == 1023) off[n] = sums[1023];
}

__global__ void scatter_kernel(const int* __restrict__ ei, int E, int N,
                               const int* __restrict__ off, int* __restrict__ cursor,
                               int* __restrict__ csr_src) {
    int e = blockIdx.x * blockDim.x + threadIdx.x;
    int Etot = E + N;
    if (e >= Etot) return;
    int s, d;
    if (e < E) { s = ei[e]; d = ei[E + e]; } else { s = d = e - E; }
    int pos = off[d] + atomicAdd(&cursor[d], 1);
    csr_src[pos] = s;
}

// ---------------- tiled fp32 GEMM: C[M,128] = A[M,K] @ B[K,128] (+bias, act) ----------------
// BM=64, BN=128, BK=32; 256 threads; thread computes 4 rows x 8 cols
__global__ __launch_bounds__(256) void gemm_kernel(const float* __restrict__ A,
                                                   const float* __restrict__ B,
                                                   float* __restrict__ C, int M, int K,
                                                   const float* __restrict__ bias, int act) {
    __shared__ float As[64][33];   // +1 pad: conflict-free broadcast reads
    __shared__ float Bs[32][128];
    int tid = threadIdx.x;
    int bm  = blockIdx.x * 64;
    int tx  = tid & 15;            // col group: 8 cols each
    int ty  = tid >> 4;            // row group: 4 rows each
    int c0  = tx * 8;
    int r0  = ty * 4;

    float acc[4][8];
#pragma unroll
    for (int i = 0; i < 4; ++i)
#pragma unroll
        for (int j = 0; j < 8; ++j) acc[i][j] = 0.f;

    for (int k0 = 0; k0 < K; k0 += 32) {
        // A tile 64x32 = 2048 floats -> 2 float4 per thread
#pragma unroll
        for (int t = 0; t < 2; ++t) {
            int flat = tid * 4 + t * 1024;
            int r = flat >> 5, kk = flat & 31;
            int gr = bm + r;
            float4 v = make_float4(0.f, 0.f, 0.f, 0.f);
            if (gr < M) v = *reinterpret_cast<const float4*>(&A[(size_t)gr * K + k0 + kk]);
            As[r][kk] = v.x; As[r][kk + 1] = v.y; As[r][kk + 2] = v.z; As[r][kk + 3] = v.w;
        }
        // B tile 32x128 = 4096 floats -> 4 float4 per thread
#pragma unroll
        for (int t = 0; t < 4; ++t) {
            int flat = tid * 4 + t * 1024;
            int kk = flat >> 7, c = flat & 127;
            float4 v = *reinterpret_cast<const float4*>(&B[(size_t)(k0 + kk) * 128 + c]);
            *reinterpret_cast<float4*>(&Bs[kk][c]) = v;
        }
        __syncthreads();
#pragma unroll
        for (int kk = 0; kk < 32; ++kk) {
            float a[4];
#pragma unroll
            for (int i = 0; i < 4; ++i) a[i] = As[r0 + i][kk];
            float4 b0 = *reinterpret_cast<const float4*>(&Bs[kk][c0]);
            float4 b1 = *reinterpret_cast<const float4*>(&Bs[kk][c0 + 4]);
            float b[8] = {b0.x, b0.y, b0.z, b0.w, b1.x, b1.y, b1.z, b1.w};
#pragma unroll
            for (int i = 0; i < 4; ++i)
#pragma unroll
                for (int j = 0; j < 8; ++j) acc[i][j] = fmaf(a[i], b[j], acc[i][j]);
        }
        __syncthreads();
    }

    float bia[8];
#pragma unroll
    for (int j = 0; j < 8; ++j) bia[j] = bias ? bias[c0 + j] : 0.f;
#pragma unroll
    for (int i = 0; i < 4; ++i) {
        int r = bm + r0 + i;
        if (r >= M) continue;
        float o[8];
#pragma unroll
        for (int j = 0; j < 8; ++j) {
            float v = acc[i][j] + bia[j];
            if (act) v = fmaxf(v, 0.f);
            o[j] = v;
        }
        *reinterpret_cast<float4*>(&C[(size_t)r * 128 + c0])     = make_float4(o[0], o[1], o[2], o[3]);
        *reinterpret_cast<float4*>(&C[(size_t)r * 128 + c0 + 4]) = make_float4(o[4], o[5], o[6], o[7]);
    }
}

// ---------------- per-node alpha dot products ----------------
__global__ void alphas_kernel(const float* __restrict__ h, const float* __restrict__ a_src,
                              const float* __restrict__ a_dst, float* __restrict__ as_out,
                              float* __restrict__ ad_out, int N) {
    int wave = (blockIdx.x * blockDim.x + threadIdx.x) >> 6;
    int lane = threadIdx.x & 63;
    if (wave >= N) return;
    const float* row = h + (size_t)wave * HDIM;
    float v0 = row[lane], v1 = row[lane + 64];
    float s = v0 * a_src[lane] + v1 * a_src[lane + 64];
    float d = v0 * a_dst[lane] + v1 * a_dst[lane + 64];
#pragma unroll
    for (int o = 32; o > 0; o >>= 1) { s += __shfl_down(s, o); d += __shfl_down(d, o); }
    if (lane == 0) { as_out[wave] = s; ad_out[wave] = d; }
}

// ---------------- attention aggregation: one wave per dst node ----------------
__global__ __launch_bounds__(256) void aggregate_kernel(const float* __restrict__ h,
                                 const float* __restrict__ asrc, const float* __restrict__ adst,
                                 const int* __restrict__ off, const int* __restrict__ csr_src,
                                 const float* __restrict__ bias, float* __restrict__ out,
                                 int N, int do_relu) {
    int wave = blockIdx.x * (blockDim.x >> 6) + (threadIdx.x >> 6);
    int lane = threadIdx.x & 63;
    if (wave >= N) return;
    int n = wave;
    int o0 = off[n], o1 = off[n + 1];
    float ad = adst[n];
    // pass 1: segment max (lanes parallel over edges)
    float m = -INFINITY;
    for (int i = o0 + lane; i < o1; i += 64) {
        int s = csr_src[i];
        m = fmaxf(m, lrelu(asrc[s] + ad));
    }
#pragma unroll
    for (int o = 32; o > 0; o >>= 1) m = fmaxf(m, __shfl_xor(m, o));
    // pass 2: weighted accumulation (lanes = feature dims)
    float acc0 = 0.f, acc1 = 0.f, denom = 0.f;
    for (int i = o0; i < o1; ++i) {
        int s = csr_src[i];
        float e = expf(lrelu(asrc[s] + ad) - m);
        denom += e;
        const float* hr = h + (size_t)s * HDIM;
        acc0 = fmaf(e, hr[lane], acc0);
        acc1 = fmaf(e, hr[lane + 64], acc1);
    }
    float inv = 1.f / denom;
    float r0 = acc0 * inv + bias[lane];
    float r1 = acc1 * inv + bias[lane + 64];
    if (do_relu) { r0 = fmaxf(r0, 0.f); r1 = fmaxf(r1, 0.f); }
    out[(size_t)n * HDIM + lane]      = r0;
    out[(size_t)n * HDIM + lane + 64] = r1;
}

// ---------------- MLP head: out = sigmoid(Z[M,128] @ W[128,20] + b) ----------------
__global__ __launch_bounds__(256) void head_kernel(const float* __restrict__ Z,
                                                   const float* __restrict__ W,
                                                   const float* __restrict__ b,
                                                   float* __restrict__ out, int N) {
    __shared__ float Ws[HDIM][NCLS];
    __shared__ float Zs[256][33];
    int tid = threadIdx.x;
    for (int i = tid; i < HDIM * NCLS; i += 256) Ws[i / NCLS][i % NCLS] = W[i];
    float acc[NCLS];
#pragma unroll
    for (int c = 0; c < NCLS; ++c) acc[c] = 0.f;
    int row = blockIdx.x * 256 + tid;
    for (int k0 = 0; k0 < HDIM; k0 += 32) {
        __syncthreads();
#pragma unroll
        for (int t = 0; t < 8; ++t) {
            int flat = tid * 4 + t * 1024;
            int r = flat >> 5, kk = flat & 31;
            int gr = blockIdx.x * 256 + r;
            float4 v = make_float4(0.f, 0.f, 0.f, 0.f);
            if (gr < N) v = *reinterpret_cast<const float4*>(&Z[(size_t)gr * HDIM + k0 + kk]);
            Zs[r][kk] = v.x; Zs[r][kk + 1] = v.y; Zs[r][kk + 2] = v.z; Zs[r][kk + 3] = v.w;
        }
        __syncthreads();
#pragma unroll
        for (int kk = 0; kk < 32; ++kk) {
            float a = Zs[tid][kk];
#pragma unroll
            for (int c = 0; c < NCLS; ++c) acc[c] = fmaf(a, Ws[k0 + kk][c], acc[c]);
        }
    }
    if (row < N) {
#pragma unroll
        for (int c = 0; c < NCLS; ++c) {
            float v = acc[c] + b[c];
            out[(size_t)row * NCLS + c] = 1.f / (1.f + expf(-v));
        }
    }
}

extern "C" void kernel_launch(void* const* d_in, const int* in_sizes, int n_in,
                              void* d_out, int out_size, void* d_ws, size_t ws_size,
                              hipStream_t stream) {
    const float* x      = (const float*)d_in[0];
    const int*   ei     = (const int*)d_in[1];
    const float* W1     = (const float*)d_in[2];
    const float* a_src1 = (const float*)d_in[3];
    const float* a_dst1 = (const float*)d_in[4];
    const float* b1     = (const float*)d_in[5];
    const float* W2     = (const float*)d_in[6];
    const float* a_src2 = (const float*)d_in[7];
    const float* a_dst2 = (const float*)d_in[8];
    const float* b2     = (const float*)d_in[9];
    const float* Wm1    = (const float*)d_in[10];
    const float* bm1    = (const float*)d_in[11];
    const float* Wm2    = (const float*)d_in[12];
    const float* bm2    = (const float*)d_in[13];

    int N = in_sizes[0] / F_IN;
    int E = in_sizes[1] / 2;
    int Etot = E + N;

    char* ws = (char*)d_ws;
    size_t pos = 0;
    auto alloc = [&](size_t bytes) -> void* {
        void* p = ws + pos;
        pos = (pos + bytes + 255) & ~(size_t)255;
        return p;
    };
    float* bufA   = (float*)alloc((size_t)N * HDIM * 4);
    float* bufB   = (float*)alloc((size_t)N * HDIM * 4);
    float* as_buf = (float*)alloc((size_t)N * 4);
    float* ad_buf = (float*)alloc((size_t)N * 4);
    int*   deg    = (int*)alloc((size_t)N * 4);
    int*   offs   = (int*)alloc((size_t)(N + 1) * 4);
    int*   cursor = (int*)alloc((size_t)N * 4);
    int*   csr    = (int*)alloc((size_t)Etot * 4);

    hipMemsetAsync(deg, 0, (size_t)N * 4, stream);
    hipMemsetAsync(cursor, 0, (size_t)N * 4, stream);

    int eb = (Etot + 255) / 256;
    count_kernel<<<eb, 256, 0, stream>>>(ei, E, N, deg);
    scan_kernel<<<1, 1024, 0, stream>>>(deg, offs, N);
    scatter_kernel<<<eb, 256, 0, stream>>>(ei, E, N, offs, cursor, csr);

    int gemm_blocks = (N + 63) / 64;
    int wave_blocks = (N + 3) / 4;   // 4 waves per 256-thread block

    // layer 1: h1 = x @ W1; attention; relu
    gemm_kernel<<<gemm_blocks, 256, 0, stream>>>(x, W1, bufA, N, F_IN, nullptr, 0);
    alphas_kernel<<<wave_blocks, 256, 0, stream>>>(bufA, a_src1, a_dst1, as_buf, ad_buf, N);
    aggregate_kernel<<<wave_blocks, 256, 0, stream>>>(bufA, as_buf, ad_buf, offs, csr, b1, bufB, N, 1);

    // layer 2: h2 = f1 @ W2; attention (no relu)
    gemm_kernel<<<gemm_blocks, 256, 0, stream>>>(bufB, W2, bufA, N, HDIM, nullptr, 0);
    alphas_kernel<<<wave_blocks, 256, 0, stream>>>(bufA, a_src2, a_dst2, as_buf, ad_buf, N);
    aggregate_kernel<<<wave_blocks, 256, 0, stream>>>(bufA, as_buf, ad_buf, offs, csr, b2, bufB, N, 0);

    // MLP head
    gemm_kernel<<<gemm_blocks, 256, 0, stream>>>(bufB, Wm1, bufA, N, HDIM, bm1, 1);
    head_kernel<<<(N + 255) / 256, 256, 0, stream>>>(bufA, Wm2, bm2, (float*)d_out, N);
}

// Round 2
// 391.536 us; speedup vs baseline: 1.1899x; 1.1899x over previous
//
#include <hip/hip_runtime.h>
#include <math.h>

#define F_IN 256
#define HDIM 128
#define NCLS 20
#define NEG_SLOPE 0.2f

static __device__ __forceinline__ float lrelu(float x) { return x > 0.f ? x : NEG_SLOPE * x; }

// ---------------- CSR build ----------------
__global__ void count_kernel(const int* __restrict__ ei, int E, int N, int* __restrict__ deg) {
    int e = blockIdx.x * blockDim.x + threadIdx.x;
    int Etot = E + N;
    if (e >= Etot) return;
    int d = (e < E) ? ei[E + e] : (e - E);
    atomicAdd(&deg[d], 1);
}

__global__ __launch_bounds__(1024) void scan_kernel(const int* __restrict__ deg, int* __restrict__ off, int n) {
    __shared__ int sums[1024];
    int tid = threadIdx.x;
    int chunk = (n + 1023) / 1024;
    int start = tid * chunk; if (start > n) start = n;
    int end = start + chunk; if (end > n) end = n;
    int s = 0;
    for (int i = start; i < end; ++i) s += deg[i];
    sums[tid] = s;
    __syncthreads();
    for (int d = 1; d < 1024; d <<= 1) {
        int v = (tid >= d) ? sums[tid - d] : 0;
        __syncthreads();
        sums[tid] += v;
        __syncthreads();
    }
    int prefix = (tid == 0) ? 0 : sums[tid - 1];
    for (int i = start; i < end; ++i) { off[i] = prefix; prefix += deg[i]; }
    if (tid == 1023) off[n] = sums[1023];
}

__global__ void scatter_kernel(const int* __restrict__ ei, int E, int N,
                               const int* __restrict__ off, int* __restrict__ cursor,
                               int* __restrict__ csr_src) {
    int e = blockIdx.x * blockDim.x + threadIdx.x;
    int Etot = E + N;
    if (e >= Etot) return;
    int s, d;
    if (e < E) { s = ei[e]; d = ei[E + e]; } else { s = d = e - E; }
    int pos = off[d] + atomicAdd(&cursor[d], 1);
    csr_src[pos] = s;
}

// ---------------- fp32 GEMM: C[M,128] = A[M,K] @ B[K,128] (+bias, act) ----------------
// BM=128, BN=128, BK=16; 512 threads; thread computes 8 rows x 4 cols.
// LDS is k-major (As[kk][row]) so fragment reads are ds_read_b128.
__global__ __launch_bounds__(512) void gemm_kernel(const float* __restrict__ A,
                                                   const float* __restrict__ B,
                                                   float* __restrict__ C, int M, int K,
                                                   const float* __restrict__ bias, int act) {
    __shared__ float As[16][132];   // +4 pad: staging writes 2-way (free)
    __shared__ float Bs[16][132];
    int tid = threadIdx.x;
    int bm  = blockIdx.x * 128;
    int tx  = tid & 31;            // col group: 4 cols
    int ty  = tid >> 5;            // row group: 8 rows
    int c0  = tx * 4;
    int r0  = ty * 8;

    // staging assignment
    int ar = tid >> 2;             // 0..127 (A row within tile)
    int ak = (tid & 3) << 2;       // 0,4,8,12
    int bk = tid >> 5;             // 0..15
    int bc = (tid & 31) << 2;      // 0..124
    bool aval = (bm + ar) < M;
    const float* Arow = A + (size_t)(bm + ar) * K;
    const float* Brow = B + (size_t)bk * 128 + bc;

    float acc[8][4];
#pragma unroll
    for (int i = 0; i < 8; ++i)
#pragma unroll
        for (int j = 0; j < 4; ++j) acc[i][j] = 0.f;

    // prefetch first tile
    float4 va = make_float4(0.f, 0.f, 0.f, 0.f);
    if (aval) va = *reinterpret_cast<const float4*>(Arow + ak);
    float4 vb = *reinterpret_cast<const float4*>(Brow);

    for (int k0 = 0; k0 < K; k0 += 16) {
        __syncthreads();   // previous inner-loop reads complete
        As[ak + 0][ar] = va.x; As[ak + 1][ar] = va.y;
        As[ak + 2][ar] = va.z; As[ak + 3][ar] = va.w;
        *reinterpret_cast<float4*>(&Bs[bk][bc]) = vb;
        __syncthreads();
        // prefetch next tile while computing this one
        int kn = k0 + 16;
        if (kn < K) {
            if (aval) va = *reinterpret_cast<const float4*>(Arow + kn + ak);
            vb = *reinterpret_cast<const float4*>(B + (size_t)(kn + bk) * 128 + bc);
        }
#pragma unroll
        for (int kk = 0; kk < 16; ++kk) {
            float4 a0 = *reinterpret_cast<const float4*>(&As[kk][r0]);
            float4 a1 = *reinterpret_cast<const float4*>(&As[kk][r0 + 4]);
            float4 b  = *reinterpret_cast<const float4*>(&Bs[kk][c0]);
            float av[8] = {a0.x, a0.y, a0.z, a0.w, a1.x, a1.y, a1.z, a1.w};
            float bv[4] = {b.x, b.y, b.z, b.w};
#pragma unroll
            for (int i = 0; i < 8; ++i)
#pragma unroll
                for (int j = 0; j < 4; ++j) acc[i][j] = fmaf(av[i], bv[j], acc[i][j]);
        }
    }

    float bia[4] = {0.f, 0.f, 0.f, 0.f};
    if (bias) {
        float4 bv = *reinterpret_cast<const float4*>(&bias[c0]);
        bia[0] = bv.x; bia[1] = bv.y; bia[2] = bv.z; bia[3] = bv.w;
    }
#pragma unroll
    for (int i = 0; i < 8; ++i) {
        int r = bm + r0 + i;
        if (r >= M) continue;
        float o[4];
#pragma unroll
        for (int j = 0; j < 4; ++j) {
            float v = acc[i][j] + bia[j];
            if (act) v = fmaxf(v, 0.f);
            o[j] = v;
        }
        *reinterpret_cast<float4*>(&C[(size_t)r * 128 + c0]) = make_float4(o[0], o[1], o[2], o[3]);
    }
}

// ---------------- per-node alpha dot products ----------------
// lane owns feature dims 2l, 2l+1 (float2 loads)
__global__ void alphas_kernel(const float* __restrict__ h, const float* __restrict__ a_src,
                              const float* __restrict__ a_dst, float* __restrict__ as_out,
                              float* __restrict__ ad_out, int N) {
    int wave = (blockIdx.x * blockDim.x + threadIdx.x) >> 6;
    int lane = threadIdx.x & 63;
    if (wave >= N) return;
    float2 v  = *reinterpret_cast<const float2*>(&h[(size_t)wave * HDIM + 2 * lane]);
    float2 as = *reinterpret_cast<const float2*>(&a_src[2 * lane]);
    float2 ad = *reinterpret_cast<const float2*>(&a_dst[2 * lane]);
    float s = v.x * as.x + v.y * as.y;
    float d = v.x * ad.x + v.y * ad.y;
#pragma unroll
    for (int o = 32; o > 0; o >>= 1) { s += __shfl_down(s, o); d += __shfl_down(d, o); }
    if (lane == 0) { as_out[wave] = s; ad_out[wave] = d; }
}

// ---------------- attention aggregation: one wave per dst node ----------------
// No max-shift (logits are O(1); exp is safe in fp32; coef ratio is identical).
// Phase A: 64 edges/chunk in parallel -> e_i, denom; stash (src,e) in LDS.
// Phase B: serial fma over edges; lane owns dims 2l,2l+1 -> dwordx2 gather.
__global__ __launch_bounds__(256) void aggregate_kernel(const float* __restrict__ h,
                                 const float* __restrict__ asrc, const float* __restrict__ adst,
                                 const int* __restrict__ off, const int* __restrict__ csr_src,
                                 const float* __restrict__ bias, float* __restrict__ out,
                                 int N, int do_relu) {
    __shared__ float2 sm[4][64];
    int wslot = threadIdx.x >> 6;
    int wave = blockIdx.x * 4 + wslot;
    int lane = threadIdx.x & 63;
    if (wave >= N) return;
    int n = wave;
    int o0 = off[n], o1 = off[n + 1];
    float ad = adst[n];

    float denom = 0.f;
    float2 accA = make_float2(0.f, 0.f);
    float2 accB = make_float2(0.f, 0.f);

    for (int base = o0; base < o1; base += 64) {
        int cnt = o1 - base; if (cnt > 64) cnt = 64;
        // phase A: parallel exp
        float e = 0.f; int s = 0;
        if (lane < cnt) {
            s = csr_src[base + lane];
            e = __expf(lrelu(asrc[s] + ad));
        }
        float t = e;
#pragma unroll
        for (int o = 32; o > 0; o >>= 1) t += __shfl_xor(t, o);
        denom += t;
        sm[wslot][lane] = make_float2(__int_as_float(s), e);
        // phase B: serial weighted gather (unroll x2, independent acc pairs)
        int j = 0;
        for (; j + 1 < cnt; j += 2) {
            float2 v0 = sm[wslot][j];
            float2 v1 = sm[wslot][j + 1];
            int s0 = __float_as_int(v0.x);
            int s1 = __float_as_int(v1.x);
            float2 h0 = *reinterpret_cast<const float2*>(&h[(size_t)s0 * HDIM + 2 * lane]);
            float2 h1 = *reinterpret_cast<const float2*>(&h[(size_t)s1 * HDIM + 2 * lane]);
            accA.x = fmaf(v0.y, h0.x, accA.x);
            accA.y = fmaf(v0.y, h0.y, accA.y);
            accB.x = fmaf(v1.y, h1.x, accB.x);
            accB.y = fmaf(v1.y, h1.y, accB.y);
        }
        if (j < cnt) {
            float2 v0 = sm[wslot][j];
            int s0 = __float_as_int(v0.x);
            float2 h0 = *reinterpret_cast<const float2*>(&h[(size_t)s0 * HDIM + 2 * lane]);
            accA.x = fmaf(v0.y, h0.x, accA.x);
            accA.y = fmaf(v0.y, h0.y, accA.y);
        }
    }

    float inv = 1.f / denom;
    float2 bi = *reinterpret_cast<const float2*>(&bias[2 * lane]);
    float r0 = (accA.x + accB.x) * inv + bi.x;
    float r1 = (accA.y + accB.y) * inv + bi.y;
    if (do_relu) { r0 = fmaxf(r0, 0.f); r1 = fmaxf(r1, 0.f); }
    *reinterpret_cast<float2*>(&out[(size_t)n * HDIM + 2 * lane]) = make_float2(r0, r1);
}

// ---------------- MLP head: out = sigmoid(Z[M,128] @ W[128,20] + b) ----------------
__global__ __launch_bounds__(256) void head_kernel(const float* __restrict__ Z,
                                                   const float* __restrict__ W,
                                                   const float* __restrict__ b,
                                                   float* __restrict__ out, int N) {
    __shared__ float Ws[HDIM][NCLS];
    __shared__ float Zs[256][33];
    int tid = threadIdx.x;
    for (int i = tid; i < HDIM * NCLS; i += 256) Ws[i / NCLS][i % NCLS] = W[i];
    float acc[NCLS];
#pragma unroll
    for (int c = 0; c < NCLS; ++c) acc[c] = 0.f;
    int row = blockIdx.x * 256 + tid;
    for (int k0 = 0; k0 < HDIM; k0 += 32) {
        __syncthreads();
#pragma unroll
        for (int t = 0; t < 8; ++t) {
            int flat = tid * 4 + t * 1024;
            int r = flat >> 5, kk = flat & 31;
            int gr = blockIdx.x * 256 + r;
            float4 v = make_float4(0.f, 0.f, 0.f, 0.f);
            if (gr < N) v = *reinterpret_cast<const float4*>(&Z[(size_t)gr * HDIM + k0 + kk]);
            Zs[r][kk] = v.x; Zs[r][kk + 1] = v.y; Zs[r][kk + 2] = v.z; Zs[r][kk + 3] = v.w;
        }
        __syncthreads();
#pragma unroll
        for (int kk = 0; kk < 32; ++kk) {
            float a = Zs[tid][kk];
#pragma unroll
            for (int c = 0; c < NCLS; ++c) acc[c] = fmaf(a, Ws[k0 + kk][c], acc[c]);
        }
    }
    if (row < N) {
#pragma unroll
        for (int c = 0; c < NCLS; ++c) {
            float v = acc[c] + b[c];
            out[(size_t)row * NCLS + c] = 1.f / (1.f + expf(-v));
        }
    }
}

extern "C" void kernel_launch(void* const* d_in, const int* in_sizes, int n_in,
                              void* d_out, int out_size, void* d_ws, size_t ws_size,
                              hipStream_t stream) {
    const float* x      = (const float*)d_in[0];
    const int*   ei     = (const int*)d_in[1];
    const float* W1     = (const float*)d_in[2];
    const float* a_src1 = (const float*)d_in[3];
    const float* a_dst1 = (const float*)d_in[4];
    const float* b1     = (const float*)d_in[5];
    const float* W2     = (const float*)d_in[6];
    const float* a_src2 = (const float*)d_in[7];
    const float* a_dst2 = (const float*)d_in[8];
    const float* b2     = (const float*)d_in[9];
    const float* Wm1    = (const float*)d_in[10];
    const float* bm1    = (const float*)d_in[11];
    const float* Wm2    = (const float*)d_in[12];
    const float* bm2    = (const float*)d_in[13];

    int N = in_sizes[0] / F_IN;
    int E = in_sizes[1] / 2;
    int Etot = E + N;

    char* ws = (char*)d_ws;
    size_t pos = 0;
    auto alloc = [&](size_t bytes) -> void* {
        void* p = ws + pos;
        pos = (pos + bytes + 255) & ~(size_t)255;
        return p;
    };
    float* bufA   = (float*)alloc((size_t)N * HDIM * 4);
    float* bufB   = (float*)alloc((size_t)N * HDIM * 4);
    float* as_buf = (float*)alloc((size_t)N * 4);
    float* ad_buf = (float*)alloc((size_t)N * 4);
    int*   deg    = (int*)alloc((size_t)N * 4);
    int*   offs   = (int*)alloc((size_t)(N + 1) * 4);
    int*   cursor = (int*)alloc((size_t)N * 4);
    int*   csr    = (int*)alloc((size_t)Etot * 4);

    hipMemsetAsync(deg, 0, (size_t)N * 4, stream);
    hipMemsetAsync(cursor, 0, (size_t)N * 4, stream);

    int eb = (Etot + 255) / 256;
    count_kernel<<<eb, 256, 0, stream>>>(ei, E, N, deg);
    scan_kernel<<<1, 1024, 0, stream>>>(deg, offs, N);
    scatter_kernel<<<eb, 256, 0, stream>>>(ei, E, N, offs, cursor, csr);

    int gemm_blocks = (N + 127) / 128;
    int wave_blocks = (N + 3) / 4;   // 4 waves per 256-thread block

    // layer 1: h1 = x @ W1; attention; relu
    gemm_kernel<<<gemm_blocks, 512, 0, stream>>>(x, W1, bufA, N, F_IN, nullptr, 0);
    alphas_kernel<<<wave_blocks, 256, 0, stream>>>(bufA, a_src1, a_dst1, as_buf, ad_buf, N);
    aggregate_kernel<<<wave_blocks, 256, 0, stream>>>(bufA, as_buf, ad_buf, offs, csr, b1, bufB, N, 1);

    // layer 2: h2 = f1 @ W2; attention (no relu)
    gemm_kernel<<<gemm_blocks, 512, 0, stream>>>(bufB, W2, bufA, N, HDIM, nullptr, 0);
    alphas_kernel<<<wave_blocks, 256, 0, stream>>>(bufA, a_src2, a_dst2, as_buf, ad_buf, N);
    aggregate_kernel<<<wave_blocks, 256, 0, stream>>>(bufA, as_buf, ad_buf, offs, csr, b2, bufB, N, 0);

    // MLP head
    gemm_kernel<<<gemm_blocks, 512, 0, stream>>>(bufB, Wm1, bufA, N, HDIM, bm1, 1);
    head_kernel<<<(N + 255) / 256, 256, 0, stream>>>(bufA, Wm2, bm2, (float*)d_out, N);
}

// Round 3
// 323.590 us; speedup vs baseline: 1.4397x; 1.2100x over previous
//
#include <hip/hip_runtime.h>
#include <math.h>

#define F_IN 256
#define HDIM 128
#define NCLS 20
#define NEG_SLOPE 0.2f
#define SCAN_CHUNK 1024

static __device__ __forceinline__ float lrelu(float x) { return x > 0.f ? x : NEG_SLOPE * x; }

// ---------------- CSR build ----------------
__global__ void count_kernel(const int* __restrict__ ei, int E, int N, int* __restrict__ deg) {
    int e = blockIdx.x * blockDim.x + threadIdx.x;
    int Etot = E + N;
    if (e >= Etot) return;
    int d = (e < E) ? ei[E + e] : (e - E);
    atomicAdd(&deg[d], 1);
}

// 3-phase device-wide exclusive scan of deg[0..n) -> off[0..n], off[n]=total
__global__ __launch_bounds__(256) void scan_reduce_kernel(const int* __restrict__ deg, int n,
                                                          int* __restrict__ bsums) {
    int base = blockIdx.x * SCAN_CHUNK + threadIdx.x * 4;
    int s = 0;
    if (base + 3 < n) {
        int4 v = *reinterpret_cast<const int4*>(&deg[base]);
        s = v.x + v.y + v.z + v.w;
    } else {
#pragma unroll
        for (int j = 0; j < 4; ++j) if (base + j < n) s += deg[base + j];
    }
#pragma unroll
    for (int o = 32; o > 0; o >>= 1) s += __shfl_down(s, o);
    __shared__ int ws[4];
    int lane = threadIdx.x & 63, w = threadIdx.x >> 6;
    if (lane == 0) ws[w] = s;
    __syncthreads();
    if (threadIdx.x == 0) bsums[blockIdx.x] = ws[0] + ws[1] + ws[2] + ws[3];
}

__global__ __launch_bounds__(256) void scan_bsums_kernel(int* __restrict__ bsums, int nb,
                                                         int* __restrict__ off, int n) {
    __shared__ int sh[256];
    int tid = threadIdx.x;
    int v = (tid < nb) ? bsums[tid] : 0;
    sh[tid] = v;
    __syncthreads();
    for (int d = 1; d < 256; d <<= 1) {
        int t = (tid >= d) ? sh[tid - d] : 0;
        __syncthreads();
        sh[tid] += t;
        __syncthreads();
    }
    if (tid < nb) bsums[tid] = sh[tid] - v;    // exclusive prefix
    if (tid == 255) off[n] = sh[255];          // total
}

__global__ __launch_bounds__(256) void scan_down_kernel(const int* __restrict__ deg, int n,
                                                        const int* __restrict__ bpre,
                                                        int* __restrict__ off) {
    int base = blockIdx.x * SCAN_CHUNK + threadIdx.x * 4;
    int v0 = 0, v1 = 0, v2 = 0, v3 = 0;
    if (base + 3 < n) {
        int4 t = *reinterpret_cast<const int4*>(&deg[base]);
        v0 = t.x; v1 = t.y; v2 = t.z; v3 = t.w;
    } else {
        if (base + 0 < n) v0 = deg[base + 0];
        if (base + 1 < n) v1 = deg[base + 1];
        if (base + 2 < n) v2 = deg[base + 2];
        if (base + 3 < n) v3 = deg[base + 3];
    }
    int tsum = v0 + v1 + v2 + v3;
    int lane = threadIdx.x & 63, w = threadIdx.x >> 6;
    int inc = tsum;
#pragma unroll
    for (int o = 1; o < 64; o <<= 1) {
        int t = __shfl_up(inc, o);
        if (lane >= o) inc += t;
    }
    int texc = inc - tsum;
    __shared__ int wsum[4];
    if (lane == 63) wsum[w] = inc;
    __syncthreads();
    int wpre = 0;
    for (int i = 0; i < w; ++i) wpre += wsum[i];
    int p = bpre[blockIdx.x] + wpre + texc;
    if (base + 3 < n) {
        int4 o4;
        o4.x = p;
        o4.y = p + v0;
        o4.z = p + v0 + v1;
        o4.w = p + v0 + v1 + v2;
        *reinterpret_cast<int4*>(&off[base]) = o4;
    } else {
        int run = p;
        if (base + 0 < n) { off[base + 0] = run; run += v0; }
        if (base + 1 < n) { off[base + 1] = run; run += v1; }
        if (base + 2 < n) { off[base + 2] = run; run += v2; }
        if (base + 3 < n) { off[base + 3] = run; }
    }
}

__global__ void scatter_kernel(const int* __restrict__ ei, int E, int N,
                               const int* __restrict__ off, int* __restrict__ cursor,
                               int* __restrict__ csr_src) {
    int e = blockIdx.x * blockDim.x + threadIdx.x;
    int Etot = E + N;
    if (e >= Etot) return;
    int s, d;
    if (e < E) { s = ei[e]; d = ei[E + e]; } else { s = d = e - E; }
    int pos = off[d] + atomicAdd(&cursor[d], 1);
    csr_src[pos] = s;
}

// ---------------- fp32 GEMM: C[M,128] = A[M,K] @ B[K,128] (+bias, act) ----------------
// BM=128, BN=128, BK=16; 512 threads; thread computes 8 rows x 4 cols.
// LDS is k-major (As[kk][row]) so fragment reads are ds_read_b128.
__global__ __launch_bounds__(512) void gemm_kernel(const float* __restrict__ A,
                                                   const float* __restrict__ B,
                                                   float* __restrict__ C, int M, int K,
                                                   const float* __restrict__ bias, int act) {
    __shared__ float As[16][132];   // +4 pad: staging writes 2-way (free)
    __shared__ float Bs[16][132];
    int tid = threadIdx.x;
    int bm  = blockIdx.x * 128;
    int tx  = tid & 31;            // col group: 4 cols
    int ty  = tid >> 5;            // row group: 8 rows
    int c0  = tx * 4;
    int r0  = ty * 8;

    int ar = tid >> 2;             // 0..127 (A row within tile)
    int ak = (tid & 3) << 2;       // 0,4,8,12
    int bk = tid >> 5;             // 0..15
    int bc = (tid & 31) << 2;      // 0..124
    bool aval = (bm + ar) < M;
    const float* Arow = A + (size_t)(bm + ar) * K;
    const float* Brow = B + (size_t)bk * 128 + bc;

    float acc[8][4];
#pragma unroll
    for (int i = 0; i < 8; ++i)
#pragma unroll
        for (int j = 0; j < 4; ++j) acc[i][j] = 0.f;

    float4 va = make_float4(0.f, 0.f, 0.f, 0.f);
    if (aval) va = *reinterpret_cast<const float4*>(Arow + ak);
    float4 vb = *reinterpret_cast<const float4*>(Brow);

    for (int k0 = 0; k0 < K; k0 += 16) {
        __syncthreads();
        As[ak + 0][ar] = va.x; As[ak + 1][ar] = va.y;
        As[ak + 2][ar] = va.z; As[ak + 3][ar] = va.w;
        *reinterpret_cast<float4*>(&Bs[bk][bc]) = vb;
        __syncthreads();
        int kn = k0 + 16;
        if (kn < K) {
            if (aval) va = *reinterpret_cast<const float4*>(Arow + kn + ak);
            vb = *reinterpret_cast<const float4*>(B + (size_t)(kn + bk) * 128 + bc);
        }
#pragma unroll
        for (int kk = 0; kk < 16; ++kk) {
            float4 a0 = *reinterpret_cast<const float4*>(&As[kk][r0]);
            float4 a1 = *reinterpret_cast<const float4*>(&As[kk][r0 + 4]);
            float4 b  = *reinterpret_cast<const float4*>(&Bs[kk][c0]);
            float av[8] = {a0.x, a0.y, a0.z, a0.w, a1.x, a1.y, a1.z, a1.w};
            float bv[4] = {b.x, b.y, b.z, b.w};
#pragma unroll
            for (int i = 0; i < 8; ++i)
#pragma unroll
                for (int j = 0; j < 4; ++j) acc[i][j] = fmaf(av[i], bv[j], acc[i][j]);
        }
    }

    float bia[4] = {0.f, 0.f, 0.f, 0.f};
    if (bias) {
        float4 bv = *reinterpret_cast<const float4*>(&bias[c0]);
        bia[0] = bv.x; bia[1] = bv.y; bia[2] = bv.z; bia[3] = bv.w;
    }
#pragma unroll
    for (int i = 0; i < 8; ++i) {
        int r = bm + r0 + i;
        if (r >= M) continue;
        float o[4];
#pragma unroll
        for (int j = 0; j < 4; ++j) {
            float v = acc[i][j] + bia[j];
            if (act) v = fmaxf(v, 0.f);
            o[j] = v;
        }
        *reinterpret_cast<float4*>(&C[(size_t)r * 128 + c0]) = make_float4(o[0], o[1], o[2], o[3]);
    }
}

// ---------------- per-node alpha dot products ----------------
__global__ void alphas_kernel(const float* __restrict__ h, const float* __restrict__ a_src,
                              const float* __restrict__ a_dst, float* __restrict__ as_out,
                              float* __restrict__ ad_out, int N) {
    int wave = (blockIdx.x * blockDim.x + threadIdx.x) >> 6;
    int lane = threadIdx.x & 63;
    if (wave >= N) return;
    float2 v  = *reinterpret_cast<const float2*>(&h[(size_t)wave * HDIM + 2 * lane]);
    float2 as = *reinterpret_cast<const float2*>(&a_src[2 * lane]);
    float2 ad = *reinterpret_cast<const float2*>(&a_dst[2 * lane]);
    float s = v.x * as.x + v.y * as.y;
    float d = v.x * ad.x + v.y * ad.y;
#pragma unroll
    for (int o = 32; o > 0; o >>= 1) { s += __shfl_down(s, o); d += __shfl_down(d, o); }
    if (lane == 0) { as_out[wave] = s; ad_out[wave] = d; }
}

// ---------------- attention aggregation: one wave per dst node ----------------
__global__ __launch_bounds__(256) void aggregate_kernel(const float* __restrict__ h,
                                 const float* __restrict__ asrc, const float* __restrict__ adst,
                                 const int* __restrict__ off, const int* __restrict__ csr_src,
                                 const float* __restrict__ bias, float* __restrict__ out,
                                 int N, int do_relu) {
    __shared__ float2 sm[4][64];
    int wslot = threadIdx.x >> 6;
    int wave = blockIdx.x * 4 + wslot;
    int lane = threadIdx.x & 63;
    if (wave >= N) return;
    int n = wave;
    int o0 = off[n], o1 = off[n + 1];
    float ad = adst[n];

    float denom = 0.f;
    float2 accA = make_float2(0.f, 0.f);
    float2 accB = make_float2(0.f, 0.f);

    for (int base = o0; base < o1; base += 64) {
        int cnt = o1 - base; if (cnt > 64) cnt = 64;
        float e = 0.f; int s = 0;
        if (lane < cnt) {
            s = csr_src[base + lane];
            e = __expf(lrelu(asrc[s] + ad));
        }
        float t = e;
#pragma unroll
        for (int o = 32; o > 0; o >>= 1) t += __shfl_xor(t, o);
        denom += t;
        sm[wslot][lane] = make_float2(__int_as_float(s), e);
        int j = 0;
        for (; j + 1 < cnt; j += 2) {
            float2 v0 = sm[wslot][j];
            float2 v1 = sm[wslot][j + 1];
            int s0 = __float_as_int(v0.x);
            int s1 = __float_as_int(v1.x);
            float2 h0 = *reinterpret_cast<const float2*>(&h[(size_t)s0 * HDIM + 2 * lane]);
            float2 h1 = *reinterpret_cast<const float2*>(&h[(size_t)s1 * HDIM + 2 * lane]);
            accA.x = fmaf(v0.y, h0.x, accA.x);
            accA.y = fmaf(v0.y, h0.y, accA.y);
            accB.x = fmaf(v1.y, h1.x, accB.x);
            accB.y = fmaf(v1.y, h1.y, accB.y);
        }
        if (j < cnt) {
            float2 v0 = sm[wslot][j];
            int s0 = __float_as_int(v0.x);
            float2 h0 = *reinterpret_cast<const float2*>(&h[(size_t)s0 * HDIM + 2 * lane]);
            accA.x = fmaf(v0.y, h0.x, accA.x);
            accA.y = fmaf(v0.y, h0.y, accA.y);
        }
    }

    float inv = 1.f / denom;
    float2 bi = *reinterpret_cast<const float2*>(&bias[2 * lane]);
    float r0 = (accA.x + accB.x) * inv + bi.x;
    float r1 = (accA.y + accB.y) * inv + bi.y;
    if (do_relu) { r0 = fmaxf(r0, 0.f); r1 = fmaxf(r1, 0.f); }
    *reinterpret_cast<float2*>(&out[(size_t)n * HDIM + 2 * lane]) = make_float2(r0, r1);
}

// ---------------- MLP head: out = sigmoid(Z[M,128] @ W[128,20] + b) ----------------
__global__ __launch_bounds__(256) void head_kernel(const float* __restrict__ Z,
                                                   const float* __restrict__ W,
                                                   const float* __restrict__ b,
                                                   float* __restrict__ out, int N) {
    __shared__ float Ws[HDIM][NCLS];
    __shared__ float Zs[256][33];
    int tid = threadIdx.x;
    for (int i = tid; i < HDIM * NCLS; i += 256) Ws[i / NCLS][i % NCLS] = W[i];
    float acc[NCLS];
#pragma unroll
    for (int c = 0; c < NCLS; ++c) acc[c] = 0.f;
    int row = blockIdx.x * 256 + tid;
    for (int k0 = 0; k0 < HDIM; k0 += 32) {
        __syncthreads();
#pragma unroll
        for (int t = 0; t < 8; ++t) {
            int flat = tid * 4 + t * 1024;
            int r = flat >> 5, kk = flat & 31;
            int gr = blockIdx.x * 256 + r;
            float4 v = make_float4(0.f, 0.f, 0.f, 0.f);
            if (gr < N) v = *reinterpret_cast<const float4*>(&Z[(size_t)gr * HDIM + k0 + kk]);
            Zs[r][kk] = v.x; Zs[r][kk + 1] = v.y; Zs[r][kk + 2] = v.z; Zs[r][kk + 3] = v.w;
        }
        __syncthreads();
#pragma unroll
        for (int kk = 0; kk < 32; ++kk) {
            float a = Zs[tid][kk];
#pragma unroll
            for (int c = 0; c < NCLS; ++c) acc[c] = fmaf(a, Ws[k0 + kk][c], acc[c]);
        }
    }
    if (row < N) {
#pragma unroll
        for (int c = 0; c < NCLS; ++c) {
            float v = acc[c] + b[c];
            out[(size_t)row * NCLS + c] = 1.f / (1.f + expf(-v));
        }
    }
}

extern "C" void kernel_launch(void* const* d_in, const int* in_sizes, int n_in,
                              void* d_out, int out_size, void* d_ws, size_t ws_size,
                              hipStream_t stream) {
    const float* x      = (const float*)d_in[0];
    const int*   ei     = (const int*)d_in[1];
    const float* W1     = (const float*)d_in[2];
    const float* a_src1 = (const float*)d_in[3];
    const float* a_dst1 = (const float*)d_in[4];
    const float* b1     = (const float*)d_in[5];
    const float* W2     = (const float*)d_in[6];
    const float* a_src2 = (const float*)d_in[7];
    const float* a_dst2 = (const float*)d_in[8];
    const float* b2     = (const float*)d_in[9];
    const float* Wm1    = (const float*)d_in[10];
    const float* bm1    = (const float*)d_in[11];
    const float* Wm2    = (const float*)d_in[12];
    const float* bm2    = (const float*)d_in[13];

    int N = in_sizes[0] / F_IN;
    int E = in_sizes[1] / 2;
    int Etot = E + N;

    char* ws = (char*)d_ws;
    size_t pos = 0;
    auto alloc = [&](size_t bytes) -> void* {
        void* p = ws + pos;
        pos = (pos + bytes + 255) & ~(size_t)255;
        return p;
    };
    float* bufA   = (float*)alloc((size_t)N * HDIM * 4);
    float* bufB   = (float*)alloc((size_t)N * HDIM * 4);
    float* as_buf = (float*)alloc((size_t)N * 4);
    float* ad_buf = (float*)alloc((size_t)N * 4);
    int*   deg    = (int*)alloc((size_t)N * 4);
    int*   offs   = (int*)alloc((size_t)(N + 1) * 4);
    int*   cursor = (int*)alloc((size_t)N * 4);
    int*   csr    = (int*)alloc((size_t)Etot * 4);
    int*   bsums  = (int*)alloc(256 * 4);

    hipMemsetAsync(deg, 0, (size_t)N * 4, stream);
    hipMemsetAsync(cursor, 0, (size_t)N * 4, stream);

    int eb = (Etot + 255) / 256;
    int nb = (N + SCAN_CHUNK - 1) / SCAN_CHUNK;
    count_kernel<<<eb, 256, 0, stream>>>(ei, E, N, deg);
    scan_reduce_kernel<<<nb, 256, 0, stream>>>(deg, N, bsums);
    scan_bsums_kernel<<<1, 256, 0, stream>>>(bsums, nb, offs, N);
    scan_down_kernel<<<nb, 256, 0, stream>>>(deg, N, bsums, offs);
    scatter_kernel<<<eb, 256, 0, stream>>>(ei, E, N, offs, cursor, csr);

    int gemm_blocks = (N + 127) / 128;
    int wave_blocks = (N + 3) / 4;

    gemm_kernel<<<gemm_blocks, 512, 0, stream>>>(x, W1, bufA, N, F_IN, nullptr, 0);
    alphas_kernel<<<wave_blocks, 256, 0, stream>>>(bufA, a_src1, a_dst1, as_buf, ad_buf, N);
    aggregate_kernel<<<wave_blocks, 256, 0, stream>>>(bufA, as_buf, ad_buf, offs, csr, b1, bufB, N, 1);

    gemm_kernel<<<gemm_blocks, 512, 0, stream>>>(bufB, W2, bufA, N, HDIM, nullptr, 0);
    alphas_kernel<<<wave_blocks, 256, 0, stream>>>(bufA, a_src2, a_dst2, as_buf, ad_buf, N);
    aggregate_kernel<<<wave_blocks, 256, 0, stream>>>(bufA, as_buf, ad_buf, offs, csr, b2, bufB, N, 0);

    gemm_kernel<<<gemm_blocks, 512, 0, stream>>>(bufB, Wm1, bufA, N, HDIM, bm1, 1);
    head_kernel<<<(N + 255) / 256, 256, 0, stream>>>(bufA, Wm2, bm2, (float*)d_out, N);
}

// Round 4
// 305.497 us; speedup vs baseline: 1.5250x; 1.0592x over previous
//
#include <hip/hip_runtime.h>
#include <math.h>

#define F_IN 256
#define HDIM 128
#define NCLS 20
#define NEG_SLOPE 0.2f
#define SCAN_CHUNK 1024

typedef short bf16x8 __attribute__((ext_vector_type(8)));
typedef float f32x4 __attribute__((ext_vector_type(4)));

static __device__ __forceinline__ float lrelu(float x) { return x > 0.f ? x : NEG_SLOPE * x; }

// RNE fp32 -> bf16 (finite inputs)
static __device__ __forceinline__ unsigned short f2bf(float x) {
    unsigned u = __float_as_uint(x);
    unsigned r = u + 0x7FFFu + ((u >> 16) & 1u);
    return (unsigned short)(r >> 16);
}
static __device__ __forceinline__ float bf2f(unsigned short h) {
    return __uint_as_float(((unsigned)h) << 16);
}

// ---------------- CSR build ----------------
__global__ void count_kernel(const int* __restrict__ ei, int E, int N, int* __restrict__ deg) {
    int e = blockIdx.x * blockDim.x + threadIdx.x;
    int Etot = E + N;
    if (e >= Etot) return;
    int d = (e < E) ? ei[E + e] : (e - E);
    atomicAdd(&deg[d], 1);
}

__global__ __launch_bounds__(256) void scan_reduce_kernel(const int* __restrict__ deg, int n,
                                                          int* __restrict__ bsums) {
    int base = blockIdx.x * SCAN_CHUNK + threadIdx.x * 4;
    int s = 0;
    if (base + 3 < n) {
        int4 v = *reinterpret_cast<const int4*>(&deg[base]);
        s = v.x + v.y + v.z + v.w;
    } else {
#pragma unroll
        for (int j = 0; j < 4; ++j) if (base + j < n) s += deg[base + j];
    }
#pragma unroll
    for (int o = 32; o > 0; o >>= 1) s += __shfl_down(s, o);
    __shared__ int ws[4];
    int lane = threadIdx.x & 63, w = threadIdx.x >> 6;
    if (lane == 0) ws[w] = s;
    __syncthreads();
    if (threadIdx.x == 0) bsums[blockIdx.x] = ws[0] + ws[1] + ws[2] + ws[3];
}

__global__ __launch_bounds__(256) void scan_bsums_kernel(int* __restrict__ bsums, int nb,
                                                         int* __restrict__ off, int n) {
    __shared__ int sh[256];
    int tid = threadIdx.x;
    int v = (tid < nb) ? bsums[tid] : 0;
    sh[tid] = v;
    __syncthreads();
    for (int d = 1; d < 256; d <<= 1) {
        int t = (tid >= d) ? sh[tid - d] : 0;
        __syncthreads();
        sh[tid] += t;
        __syncthreads();
    }
    if (tid < nb) bsums[tid] = sh[tid] - v;
    if (tid == 255) off[n] = sh[255];
}

__global__ __launch_bounds__(256) void scan_down_kernel(const int* __restrict__ deg, int n,
                                                        const int* __restrict__ bpre,
                                                        int* __restrict__ off) {
    int base = blockIdx.x * SCAN_CHUNK + threadIdx.x * 4;
    int v0 = 0, v1 = 0, v2 = 0, v3 = 0;
    if (base + 3 < n) {
        int4 t = *reinterpret_cast<const int4*>(&deg[base]);
        v0 = t.x; v1 = t.y; v2 = t.z; v3 = t.w;
    } else {
        if (base + 0 < n) v0 = deg[base + 0];
        if (base + 1 < n) v1 = deg[base + 1];
        if (base + 2 < n) v2 = deg[base + 2];
        if (base + 3 < n) v3 = deg[base + 3];
    }
    int tsum = v0 + v1 + v2 + v3;
    int lane = threadIdx.x & 63, w = threadIdx.x >> 6;
    int inc = tsum;
#pragma unroll
    for (int o = 1; o < 64; o <<= 1) {
        int t = __shfl_up(inc, o);
        if (lane >= o) inc += t;
    }
    int texc = inc - tsum;
    __shared__ int wsum[4];
    if (lane == 63) wsum[w] = inc;
    __syncthreads();
    int wpre = 0;
    for (int i = 0; i < w; ++i) wpre += wsum[i];
    int p = bpre[blockIdx.x] + wpre + texc;
    if (base + 3 < n) {
        int4 o4;
        o4.x = p; o4.y = p + v0; o4.z = p + v0 + v1; o4.w = p + v0 + v1 + v2;
        *reinterpret_cast<int4*>(&off[base]) = o4;
    } else {
        int run = p;
        if (base + 0 < n) { off[base + 0] = run; run += v0; }
        if (base + 1 < n) { off[base + 1] = run; run += v1; }
        if (base + 2 < n) { off[base + 2] = run; run += v2; }
        if (base + 3 < n) { off[base + 3] = run; }
    }
}

__global__ void scatter_kernel(const int* __restrict__ ei, int E, int N,
                               const int* __restrict__ off, int* __restrict__ cursor,
                               int* __restrict__ csr_src) {
    int e = blockIdx.x * blockDim.x + threadIdx.x;
    int Etot = E + N;
    if (e >= Etot) return;
    int s, d;
    if (e < E) { s = ei[e]; d = ei[E + e]; } else { s = d = e - E; }
    int pos = off[d] + atomicAdd(&cursor[d], 1);
    csr_src[pos] = s;
}

// ---------------- fp32 -> (hi,lo) bf16 planes ----------------
__global__ __launch_bounds__(256) void convert_hilo_kernel(const float* __restrict__ in,
                                                           unsigned short* __restrict__ hi,
                                                           unsigned short* __restrict__ lo,
                                                           long n4) {
    long i = (long)blockIdx.x * blockDim.x + threadIdx.x;
    if (i >= n4) return;
    float4 v = *reinterpret_cast<const float4*>(&in[i * 4]);
    ushort4 h, l;
    h.x = f2bf(v.x); l.x = f2bf(v.x - bf2f(h.x));
    h.y = f2bf(v.y); l.y = f2bf(v.y - bf2f(h.y));
    h.z = f2bf(v.z); l.z = f2bf(v.z - bf2f(h.z));
    h.w = f2bf(v.w); l.w = f2bf(v.w - bf2f(h.w));
    *reinterpret_cast<ushort4*>(&hi[i * 4]) = h;
    *reinterpret_cast<ushort4*>(&lo[i * 4]) = l;
}

// ---------------- pack weights into MFMA B-fragment order ----------------
// layout: out[(((ks*8+cf)*2+h)*64 + lane)*8 + i] = part(B[ks*32+(lane>>4)*8+i][cf*16+(lane&15)])
// tiles: W1 (K=256): t 0..63 ; W2 (K=128): t 64..95 ; Wm1 (K=128): t 96..127
__global__ __launch_bounds__(64) void pack_b_kernel(const float* __restrict__ W1,
                                                    const float* __restrict__ W2,
                                                    const float* __restrict__ Wm1,
                                                    unsigned short* __restrict__ p1,
                                                    unsigned short* __restrict__ p2,
                                                    unsigned short* __restrict__ p3) {
    int t = blockIdx.x;
    int lane = threadIdx.x;
    const float* B; unsigned short* out; int r;
    if (t < 64)      { B = W1;  out = p1; r = t; }
    else if (t < 96) { B = W2;  out = p2; r = t - 64; }
    else             { B = Wm1; out = p3; r = t - 96; }
    int ks = r >> 3, cf = r & 7;
    int c  = cf * 16 + (lane & 15);
    int k0 = ks * 32 + (lane >> 4) * 8;
    unsigned short h8[8], l8[8];
#pragma unroll
    for (int i = 0; i < 8; ++i) {
        float v = B[(size_t)(k0 + i) * 128 + c];
        h8[i] = f2bf(v);
        l8[i] = f2bf(v - bf2f(h8[i]));
    }
    size_t base = (((size_t)(ks * 8 + cf) * 2) * 64 + lane) * 8;
#pragma unroll
    for (int i = 0; i < 8; ++i) { out[base + i] = h8[i]; out[base + 512 + i] = l8[i]; }
}

// ---------------- MFMA GEMM: C[M,128] = (Ahi+Alo)[M,K] @ Bpacked[K,128] ----------------
// 3-term split-bf16; no LDS, no barriers. Block = 4 waves (2x2), wave = 32 rows x 64 cols.
__global__ __launch_bounds__(256) void gemm_mfma_kernel(const unsigned short* __restrict__ Ahi,
                                                        const unsigned short* __restrict__ Alo,
                                                        const unsigned short* __restrict__ Bp,
                                                        float* __restrict__ C, int M, int K,
                                                        const float* __restrict__ bias, int act) {
    int tid = threadIdx.x;
    int lane = tid & 63;
    int wid = tid >> 6;
    int wr = wid >> 1, wc = wid & 1;
    int bm = blockIdx.x * 64;
    int l15 = lane & 15, l4 = lane >> 4;
    int row0 = bm + wr * 32 + l15;
    int koff = l4 * 8;
    const bf16x8 zf = {0, 0, 0, 0, 0, 0, 0, 0};

    f32x4 acc[2][4];
#pragma unroll
    for (int m = 0; m < 2; ++m)
#pragma unroll
        for (int j = 0; j < 4; ++j) acc[m][j] = (f32x4){0.f, 0.f, 0.f, 0.f};

    int ksteps = K >> 5;
    for (int ks = 0; ks < ksteps; ++ks) {
        int kbase = ks * 32 + koff;
        bf16x8 ahi[2], alo[2];
#pragma unroll
        for (int m = 0; m < 2; ++m) {
            int rr = row0 + m * 16;
            if (rr < M) {
                ahi[m] = *reinterpret_cast<const bf16x8*>(&Ahi[(size_t)rr * K + kbase]);
                alo[m] = *reinterpret_cast<const bf16x8*>(&Alo[(size_t)rr * K + kbase]);
            } else { ahi[m] = zf; alo[m] = zf; }
        }
#pragma unroll
        for (int j = 0; j < 4; ++j) {
            int cf = wc * 4 + j;
            const unsigned short* bp = Bp + (((size_t)(ks * 8 + cf) * 2) * 64 + lane) * 8;
            bf16x8 bhi = *reinterpret_cast<const bf16x8*>(bp);
            bf16x8 blo = *reinterpret_cast<const bf16x8*>(bp + 512);
            acc[0][j] = __builtin_amdgcn_mfma_f32_16x16x32_bf16(ahi[0], bhi, acc[0][j], 0, 0, 0);
            acc[1][j] = __builtin_amdgcn_mfma_f32_16x16x32_bf16(ahi[1], bhi, acc[1][j], 0, 0, 0);
            acc[0][j] = __builtin_amdgcn_mfma_f32_16x16x32_bf16(alo[0], bhi, acc[0][j], 0, 0, 0);
            acc[1][j] = __builtin_amdgcn_mfma_f32_16x16x32_bf16(alo[1], bhi, acc[1][j], 0, 0, 0);
            acc[0][j] = __builtin_amdgcn_mfma_f32_16x16x32_bf16(ahi[0], blo, acc[0][j], 0, 0, 0);
            acc[1][j] = __builtin_amdgcn_mfma_f32_16x16x32_bf16(ahi[1], blo, acc[1][j], 0, 0, 0);
        }
    }

#pragma unroll
    for (int j = 0; j < 4; ++j) {
        int col = wc * 64 + j * 16 + l15;
        float bi = bias ? bias[col] : 0.f;
#pragma unroll
        for (int m = 0; m < 2; ++m) {
            int rbase = bm + wr * 32 + m * 16 + l4 * 4;
#pragma unroll
            for (int reg = 0; reg < 4; ++reg) {
                int rr = rbase + reg;
                if (rr < M) {
                    float v = acc[m][j][reg] + bi;
                    if (act) v = fmaxf(v, 0.f);
                    C[(size_t)rr * 128 + col] = v;
                }
            }
        }
    }
}

// ---------------- per-node alpha dot products ----------------
__global__ void alphas_kernel(const float* __restrict__ h, const float* __restrict__ a_src,
                              const float* __restrict__ a_dst, float* __restrict__ as_out,
                              float* __restrict__ ad_out, int N) {
    int wave = (blockIdx.x * blockDim.x + threadIdx.x) >> 6;
    int lane = threadIdx.x & 63;
    if (wave >= N) return;
    float2 v  = *reinterpret_cast<const float2*>(&h[(size_t)wave * HDIM + 2 * lane]);
    float2 as = *reinterpret_cast<const float2*>(&a_src[2 * lane]);
    float2 ad = *reinterpret_cast<const float2*>(&a_dst[2 * lane]);
    float s = v.x * as.x + v.y * as.y;
    float d = v.x * ad.x + v.y * ad.y;
#pragma unroll
    for (int o = 32; o > 0; o >>= 1) { s += __shfl_down(s, o); d += __shfl_down(d, o); }
    if (lane == 0) { as_out[wave] = s; ad_out[wave] = d; }
}

// ---------------- attention aggregation: one wave per dst node ----------------
// Output written as (hi,lo) bf16 planes (next GEMM's A operand).
__global__ __launch_bounds__(256) void aggregate_kernel(const float* __restrict__ h,
                                 const float* __restrict__ asrc, const float* __restrict__ adst,
                                 const int* __restrict__ off, const int* __restrict__ csr_src,
                                 const float* __restrict__ bias,
                                 unsigned short* __restrict__ out_hi,
                                 unsigned short* __restrict__ out_lo,
                                 int N, int do_relu) {
    __shared__ float2 sm[4][64];
    int wslot = threadIdx.x >> 6;
    int wave = blockIdx.x * 4 + wslot;
    int lane = threadIdx.x & 63;
    if (wave >= N) return;
    int n = wave;
    int o0 = off[n], o1 = off[n + 1];
    float ad = adst[n];

    float denom = 0.f;
    float2 accA = make_float2(0.f, 0.f);
    float2 accB = make_float2(0.f, 0.f);

    for (int base = o0; base < o1; base += 64) {
        int cnt = o1 - base; if (cnt > 64) cnt = 64;
        float e = 0.f; int s = 0;
        if (lane < cnt) {
            s = csr_src[base + lane];
            e = __expf(lrelu(asrc[s] + ad));
        }
        float t = e;
#pragma unroll
        for (int o = 32; o > 0; o >>= 1) t += __shfl_xor(t, o);
        denom += t;
        sm[wslot][lane] = make_float2(__int_as_float(s), e);
        int j = 0;
        for (; j + 1 < cnt; j += 2) {
            float2 v0 = sm[wslot][j];
            float2 v1 = sm[wslot][j + 1];
            int s0 = __float_as_int(v0.x);
            int s1 = __float_as_int(v1.x);
            float2 h0 = *reinterpret_cast<const float2*>(&h[(size_t)s0 * HDIM + 2 * lane]);
            float2 h1 = *reinterpret_cast<const float2*>(&h[(size_t)s1 * HDIM + 2 * lane]);
            accA.x = fmaf(v0.y, h0.x, accA.x);
            accA.y = fmaf(v0.y, h0.y, accA.y);
            accB.x = fmaf(v1.y, h1.x, accB.x);
            accB.y = fmaf(v1.y, h1.y, accB.y);
        }
        if (j < cnt) {
            float2 v0 = sm[wslot][j];
            int s0 = __float_as_int(v0.x);
            float2 h0 = *reinterpret_cast<const float2*>(&h[(size_t)s0 * HDIM + 2 * lane]);
            accA.x = fmaf(v0.y, h0.x, accA.x);
            accA.y = fmaf(v0.y, h0.y, accA.y);
        }
    }

    float inv = 1.f / denom;
    float2 bi = *reinterpret_cast<const float2*>(&bias[2 * lane]);
    float r0 = (accA.x + accB.x) * inv + bi.x;
    float r1 = (accA.y + accB.y) * inv + bi.y;
    if (do_relu) { r0 = fmaxf(r0, 0.f); r1 = fmaxf(r1, 0.f); }
    ushort2 ho, lo;
    ho.x = f2bf(r0); lo.x = f2bf(r0 - bf2f(ho.x));
    ho.y = f2bf(r1); lo.y = f2bf(r1 - bf2f(ho.y));
    *reinterpret_cast<ushort2*>(&out_hi[(size_t)n * HDIM + 2 * lane]) = ho;
    *reinterpret_cast<ushort2*>(&out_lo[(size_t)n * HDIM + 2 * lane]) = lo;
}

// ---------------- MLP head: out = sigmoid(Z[M,128] @ W[128,20] + b) ----------------
__global__ __launch_bounds__(256) void head_kernel(const float* __restrict__ Z,
                                                   const float* __restrict__ W,
                                                   const float* __restrict__ b,
                                                   float* __restrict__ out, int N) {
    __shared__ float Ws[HDIM][NCLS];
    __shared__ float Zs[256][33];
    int tid = threadIdx.x;
    for (int i = tid; i < HDIM * NCLS; i += 256) Ws[i / NCLS][i % NCLS] = W[i];
    float acc[NCLS];
#pragma unroll
    for (int c = 0; c < NCLS; ++c) acc[c] = 0.f;
    int row = blockIdx.x * 256 + tid;
    for (int k0 = 0; k0 < HDIM; k0 += 32) {
        __syncthreads();
#pragma unroll
        for (int t = 0; t < 8; ++t) {
            int flat = tid * 4 + t * 1024;
            int r = flat >> 5, kk = flat & 31;
            int gr = blockIdx.x * 256 + r;
            float4 v = make_float4(0.f, 0.f, 0.f, 0.f);
            if (gr < N) v = *reinterpret_cast<const float4*>(&Z[(size_t)gr * HDIM + k0 + kk]);
            Zs[r][kk] = v.x; Zs[r][kk + 1] = v.y; Zs[r][kk + 2] = v.z; Zs[r][kk + 3] = v.w;
        }
        __syncthreads();
#pragma unroll
        for (int kk = 0; kk < 32; ++kk) {
            float a = Zs[tid][kk];
#pragma unroll
            for (int c = 0; c < NCLS; ++c) acc[c] = fmaf(a, Ws[k0 + kk][c], acc[c]);
        }
    }
    if (row < N) {
#pragma unroll
        for (int c = 0; c < NCLS; ++c) {
            float v = acc[c] + b[c];
            out[(size_t)row * NCLS + c] = 1.f / (1.f + expf(-v));
        }
    }
}

extern "C" void kernel_launch(void* const* d_in, const int* in_sizes, int n_in,
                              void* d_out, int out_size, void* d_ws, size_t ws_size,
                              hipStream_t stream) {
    const float* x      = (const float*)d_in[0];
    const int*   ei     = (const int*)d_in[1];
    const float* W1     = (const float*)d_in[2];
    const float* a_src1 = (const float*)d_in[3];
    const float* a_dst1 = (const float*)d_in[4];
    const float* b1     = (const float*)d_in[5];
    const float* W2     = (const float*)d_in[6];
    const float* a_src2 = (const float*)d_in[7];
    const float* a_dst2 = (const float*)d_in[8];
    const float* b2     = (const float*)d_in[9];
    const float* Wm1    = (const float*)d_in[10];
    const float* bm1    = (const float*)d_in[11];
    const float* Wm2    = (const float*)d_in[12];
    const float* bm2    = (const float*)d_in[13];

    int N = in_sizes[0] / F_IN;
    int E = in_sizes[1] / 2;
    int Etot = E + N;

    char* ws = (char*)d_ws;
    size_t pos = 0;
    auto alloc = [&](size_t bytes) -> void* {
        void* p = ws + pos;
        pos = (pos + bytes + 255) & ~(size_t)255;
        return p;
    };
    float*          bufA = (float*)alloc((size_t)N * HDIM * 4);           // h1/h2/z
    unsigned short* xhi  = (unsigned short*)alloc((size_t)N * F_IN * 2);  // also f_hi later
    unsigned short* xlo  = (unsigned short*)alloc((size_t)N * F_IN * 2);  // also f_lo later
    float* as_buf = (float*)alloc((size_t)N * 4);
    float* ad_buf = (float*)alloc((size_t)N * 4);
    int*   deg    = (int*)alloc((size_t)N * 4);
    int*   offs   = (int*)alloc((size_t)(N + 1) * 4);
    int*   cursor = (int*)alloc((size_t)N * 4);
    int*   csr    = (int*)alloc((size_t)Etot * 4);
    int*   bsums  = (int*)alloc(256 * 4);
    unsigned short* p1 = (unsigned short*)alloc(65536 * 2);  // W1 packed (K=256)
    unsigned short* p2 = (unsigned short*)alloc(32768 * 2);  // W2 packed (K=128)
    unsigned short* p3 = (unsigned short*)alloc(32768 * 2);  // Wm1 packed (K=128)

    // f_hi/f_lo reuse the x_hi/x_lo region (x planes are dead after gemm1)
    unsigned short* fhi = xhi;
    unsigned short* flo = xlo;

    hipMemsetAsync(deg, 0, (size_t)N * 4, stream);
    hipMemsetAsync(cursor, 0, (size_t)N * 4, stream);

    int eb = (Etot + 255) / 256;
    int nb = (N + SCAN_CHUNK - 1) / SCAN_CHUNK;
    count_kernel<<<eb, 256, 0, stream>>>(ei, E, N, deg);
    scan_reduce_kernel<<<nb, 256, 0, stream>>>(deg, N, bsums);
    scan_bsums_kernel<<<1, 256, 0, stream>>>(bsums, nb, offs, N);
    scan_down_kernel<<<nb, 256, 0, stream>>>(deg, N, bsums, offs);
    scatter_kernel<<<eb, 256, 0, stream>>>(ei, E, N, offs, cursor, csr);

    long n4 = (long)N * F_IN / 4;
    convert_hilo_kernel<<<(int)((n4 + 255) / 256), 256, 0, stream>>>(x, xhi, xlo, n4);
    pack_b_kernel<<<128, 64, 0, stream>>>(W1, W2, Wm1, p1, p2, p3);

    int gemm_blocks = (N + 63) / 64;
    int wave_blocks = (N + 3) / 4;

    // layer 1
    gemm_mfma_kernel<<<gemm_blocks, 256, 0, stream>>>(xhi, xlo, p1, bufA, N, F_IN, nullptr, 0);
    alphas_kernel<<<wave_blocks, 256, 0, stream>>>(bufA, a_src1, a_dst1, as_buf, ad_buf, N);
    aggregate_kernel<<<wave_blocks, 256, 0, stream>>>(bufA, as_buf, ad_buf, offs, csr, b1, fhi, flo, N, 1);

    // layer 2
    gemm_mfma_kernel<<<gemm_blocks, 256, 0, stream>>>(fhi, flo, p2, bufA, N, HDIM, nullptr, 0);
    alphas_kernel<<<wave_blocks, 256, 0, stream>>>(bufA, a_src2, a_dst2, as_buf, ad_buf, N);
    aggregate_kernel<<<wave_blocks, 256, 0, stream>>>(bufA, as_buf, ad_buf, offs, csr, b2, fhi, flo, N, 0);

    // MLP
    gemm_mfma_kernel<<<gemm_blocks, 256, 0, stream>>>(fhi, flo, p3, bufA, N, HDIM, bm1, 1);
    head_kernel<<<(N + 255) / 256, 256, 0, stream>>>(bufA, Wm2, bm2, (float*)d_out, N);
}

// Round 5
// 259.511 us; speedup vs baseline: 1.7952x; 1.1772x over previous
//
#include <hip/hip_runtime.h>
#include <math.h>

#define F_IN 256
#define HDIM 128
#define NCLS 20
#define NEG_SLOPE 0.2f
#define SCAN_CHUNK 1024

typedef short bf16x8 __attribute__((ext_vector_type(8)));
typedef float f32x4 __attribute__((ext_vector_type(4)));
typedef _Float16 f16x2 __attribute__((ext_vector_type(2)));
typedef _Float16 f16x4 __attribute__((ext_vector_type(4)));
typedef _Float16 f16x8 __attribute__((ext_vector_type(8)));

static __device__ __forceinline__ float lrelu(float x) { return x > 0.f ? x : NEG_SLOPE * x; }

// RNE fp32 -> bf16 (finite inputs)
static __device__ __forceinline__ unsigned short f2bf(float x) {
    unsigned u = __float_as_uint(x);
    unsigned r = u + 0x7FFFu + ((u >> 16) & 1u);
    return (unsigned short)(r >> 16);
}
static __device__ __forceinline__ float bf2f(unsigned short h) {
    return __uint_as_float(((unsigned)h) << 16);
}

// ---------------- CSR build ----------------
__global__ void count_kernel(const int* __restrict__ ei, int E, int N, int* __restrict__ deg) {
    int e = blockIdx.x * blockDim.x + threadIdx.x;
    int Etot = E + N;
    if (e >= Etot) return;
    int d = (e < E) ? ei[E + e] : (e - E);
    atomicAdd(&deg[d], 1);
}

__global__ __launch_bounds__(256) void scan_reduce_kernel(const int* __restrict__ deg, int n,
                                                          int* __restrict__ bsums) {
    int base = blockIdx.x * SCAN_CHUNK + threadIdx.x * 4;
    int s = 0;
    if (base + 3 < n) {
        int4 v = *reinterpret_cast<const int4*>(&deg[base]);
        s = v.x + v.y + v.z + v.w;
    } else {
#pragma unroll
        for (int j = 0; j < 4; ++j) if (base + j < n) s += deg[base + j];
    }
#pragma unroll
    for (int o = 32; o > 0; o >>= 1) s += __shfl_down(s, o);
    __shared__ int ws[4];
    int lane = threadIdx.x & 63, w = threadIdx.x >> 6;
    if (lane == 0) ws[w] = s;
    __syncthreads();
    if (threadIdx.x == 0) bsums[blockIdx.x] = ws[0] + ws[1] + ws[2] + ws[3];
}

__global__ __launch_bounds__(256) void scan_bsums_kernel(int* __restrict__ bsums, int nb,
                                                         int* __restrict__ off, int n) {
    __shared__ int sh[256];
    int tid = threadIdx.x;
    int v = (tid < nb) ? bsums[tid] : 0;
    sh[tid] = v;
    __syncthreads();
    for (int d = 1; d < 256; d <<= 1) {
        int t = (tid >= d) ? sh[tid - d] : 0;
        __syncthreads();
        sh[tid] += t;
        __syncthreads();
    }
    if (tid < nb) bsums[tid] = sh[tid] - v;
    if (tid == 255) off[n] = sh[255];
}

__global__ __launch_bounds__(256) void scan_down_kernel(const int* __restrict__ deg, int n,
                                                        const int* __restrict__ bpre,
                                                        int* __restrict__ off) {
    int base = blockIdx.x * SCAN_CHUNK + threadIdx.x * 4;
    int v0 = 0, v1 = 0, v2 = 0, v3 = 0;
    if (base + 3 < n) {
        int4 t = *reinterpret_cast<const int4*>(&deg[base]);
        v0 = t.x; v1 = t.y; v2 = t.z; v3 = t.w;
    } else {
        if (base + 0 < n) v0 = deg[base + 0];
        if (base + 1 < n) v1 = deg[base + 1];
        if (base + 2 < n) v2 = deg[base + 2];
        if (base + 3 < n) v3 = deg[base + 3];
    }
    int tsum = v0 + v1 + v2 + v3;
    int lane = threadIdx.x & 63, w = threadIdx.x >> 6;
    int inc = tsum;
#pragma unroll
    for (int o = 1; o < 64; o <<= 1) {
        int t = __shfl_up(inc, o);
        if (lane >= o) inc += t;
    }
    int texc = inc - tsum;
    __shared__ int wsum[4];
    if (lane == 63) wsum[w] = inc;
    __syncthreads();
    int wpre = 0;
    for (int i = 0; i < w; ++i) wpre += wsum[i];
    int p = bpre[blockIdx.x] + wpre + texc;
    if (base + 3 < n) {
        int4 o4;
        o4.x = p; o4.y = p + v0; o4.z = p + v0 + v1; o4.w = p + v0 + v1 + v2;
        *reinterpret_cast<int4*>(&off[base]) = o4;
    } else {
        int run = p;
        if (base + 0 < n) { off[base + 0] = run; run += v0; }
        if (base + 1 < n) { off[base + 1] = run; run += v1; }
        if (base + 2 < n) { off[base + 2] = run; run += v2; }
        if (base + 3 < n) { off[base + 3] = run; }
    }
}

__global__ void scatter_kernel(const int* __restrict__ ei, int E, int N,
                               const int* __restrict__ off, int* __restrict__ cursor,
                               int* __restrict__ csr_src) {
    int e = blockIdx.x * blockDim.x + threadIdx.x;
    int Etot = E + N;
    if (e >= Etot) return;
    int s, d;
    if (e < E) { s = ei[e]; d = ei[E + e]; } else { s = d = e - E; }
    int pos = off[d] + atomicAdd(&cursor[d], 1);
    csr_src[pos] = s;
}

// ---------------- pack weights into MFMA B-fragment order (bf16 hi/lo) ----------------
__global__ __launch_bounds__(64) void pack_b_kernel(const float* __restrict__ W1,
                                                    const float* __restrict__ W2,
                                                    const float* __restrict__ Wm1,
                                                    unsigned short* __restrict__ p1,
                                                    unsigned short* __restrict__ p2,
                                                    unsigned short* __restrict__ p3) {
    int t = blockIdx.x;
    int lane = threadIdx.x;
    const float* B; unsigned short* out; int r;
    if (t < 64)      { B = W1;  out = p1; r = t; }
    else if (t < 96) { B = W2;  out = p2; r = t - 64; }
    else             { B = Wm1; out = p3; r = t - 96; }
    int ks = r >> 3, cf = r & 7;
    int c  = cf * 16 + (lane & 15);
    int k0 = ks * 32 + (lane >> 4) * 8;
    unsigned short h8[8], l8[8];
#pragma unroll
    for (int i = 0; i < 8; ++i) {
        float v = B[(size_t)(k0 + i) * 128 + c];
        h8[i] = f2bf(v);
        l8[i] = f2bf(v - bf2f(h8[i]));
    }
    size_t base = (((size_t)(ks * 8 + cf) * 2) * 64 + lane) * 8;
#pragma unroll
    for (int i = 0; i < 8; ++i) { out[base + i] = h8[i]; out[base + 512 + i] = l8[i]; }
}

// ---------------- MFMA GEMM: C[M,128](fp16) = A[M,K] @ Bpacked[K,128] ----------------
// AFMT: 0 = fp32 A, 1 = fp16 A. A split to bf16 hi/lo in registers (3-term MFMA).
// No LDS, no barriers. Block = 4 waves (2x2), wave = 32 rows x 64 cols.
template <int AFMT>
__global__ __launch_bounds__(256) void gemm_mfma_kernel(const void* __restrict__ Aptr,
                                                        const unsigned short* __restrict__ Bp,
                                                        _Float16* __restrict__ C, int M, int K,
                                                        const float* __restrict__ bias, int act) {
    int tid = threadIdx.x;
    int lane = tid & 63;
    int wid = tid >> 6;
    int wr = wid >> 1, wc = wid & 1;
    int bm = blockIdx.x * 64;
    int l15 = lane & 15, l4 = lane >> 4;
    int row0 = bm + wr * 32 + l15;
    int koff = l4 * 8;

    f32x4 acc[2][4];
#pragma unroll
    for (int m = 0; m < 2; ++m)
#pragma unroll
        for (int j = 0; j < 4; ++j) acc[m][j] = (f32x4){0.f, 0.f, 0.f, 0.f};

    int ksteps = K >> 5;
    for (int ks = 0; ks < ksteps; ++ks) {
        int kbase = ks * 32 + koff;
        bf16x8 ahi[2], alo[2];
#pragma unroll
        for (int m = 0; m < 2; ++m) {
            int rr = row0 + m * 16;
            float av[8];
            if (rr < M) {
                if (AFMT == 0) {
                    const float* A = (const float*)Aptr;
                    float4 v0 = *reinterpret_cast<const float4*>(&A[(size_t)rr * K + kbase]);
                    float4 v1 = *reinterpret_cast<const float4*>(&A[(size_t)rr * K + kbase + 4]);
                    av[0] = v0.x; av[1] = v0.y; av[2] = v0.z; av[3] = v0.w;
                    av[4] = v1.x; av[5] = v1.y; av[6] = v1.z; av[7] = v1.w;
                } else {
                    const _Float16* A = (const _Float16*)Aptr;
                    f16x8 v = *reinterpret_cast<const f16x8*>(&A[(size_t)rr * K + kbase]);
#pragma unroll
                    for (int i = 0; i < 8; ++i) av[i] = (float)v[i];
                }
            } else {
#pragma unroll
                for (int i = 0; i < 8; ++i) av[i] = 0.f;
            }
#pragma unroll
            for (int i = 0; i < 8; ++i) {
                unsigned short h = f2bf(av[i]);
                ahi[m][i] = (short)h;
                alo[m][i] = (short)f2bf(av[i] - bf2f(h));
            }
        }
#pragma unroll
        for (int j = 0; j < 4; ++j) {
            int cf = wc * 4 + j;
            const unsigned short* bp = Bp + (((size_t)(ks * 8 + cf) * 2) * 64 + lane) * 8;
            bf16x8 bhi = *reinterpret_cast<const bf16x8*>(bp);
            bf16x8 blo = *reinterpret_cast<const bf16x8*>(bp + 512);
            acc[0][j] = __builtin_amdgcn_mfma_f32_16x16x32_bf16(ahi[0], bhi, acc[0][j], 0, 0, 0);
            acc[1][j] = __builtin_amdgcn_mfma_f32_16x16x32_bf16(ahi[1], bhi, acc[1][j], 0, 0, 0);
            acc[0][j] = __builtin_amdgcn_mfma_f32_16x16x32_bf16(alo[0], bhi, acc[0][j], 0, 0, 0);
            acc[1][j] = __builtin_amdgcn_mfma_f32_16x16x32_bf16(alo[1], bhi, acc[1][j], 0, 0, 0);
            acc[0][j] = __builtin_amdgcn_mfma_f32_16x16x32_bf16(ahi[0], blo, acc[0][j], 0, 0, 0);
            acc[1][j] = __builtin_amdgcn_mfma_f32_16x16x32_bf16(ahi[1], blo, acc[1][j], 0, 0, 0);
        }
    }

#pragma unroll
    for (int j = 0; j < 4; ++j) {
        int col = wc * 64 + j * 16 + l15;
        float bi = bias ? bias[col] : 0.f;
#pragma unroll
        for (int m = 0; m < 2; ++m) {
            int rbase = bm + wr * 32 + m * 16 + l4 * 4;
#pragma unroll
            for (int reg = 0; reg < 4; ++reg) {
                int rr = rbase + reg;
                if (rr < M) {
                    float v = acc[m][j][reg] + bi;
                    if (act) v = fmaxf(v, 0.f);
                    C[(size_t)rr * 128 + col] = (_Float16)v;
                }
            }
        }
    }
}

// ---------------- per-node alpha dot products (fp16 h) ----------------
__global__ void alphas_kernel(const _Float16* __restrict__ h, const float* __restrict__ a_src,
                              const float* __restrict__ a_dst, float* __restrict__ as_out,
                              float* __restrict__ ad_out, int N) {
    int wave = (blockIdx.x * blockDim.x + threadIdx.x) >> 6;
    int lane = threadIdx.x & 63;
    if (wave >= N) return;
    f16x2 v  = *reinterpret_cast<const f16x2*>(&h[(size_t)wave * HDIM + 2 * lane]);
    float vx = (float)v[0], vy = (float)v[1];
    float2 as = *reinterpret_cast<const float2*>(&a_src[2 * lane]);
    float2 ad = *reinterpret_cast<const float2*>(&a_dst[2 * lane]);
    float s = vx * as.x + vy * as.y;
    float d = vx * ad.x + vy * ad.y;
#pragma unroll
    for (int o = 32; o > 0; o >>= 1) { s += __shfl_down(s, o); d += __shfl_down(d, o); }
    if (lane == 0) { as_out[wave] = s; ad_out[wave] = d; }
}

// ---------------- attention aggregation: one wave per dst node (fp16 gather) ----------------
__global__ __launch_bounds__(256) void aggregate_kernel(const _Float16* __restrict__ h,
                                 const float* __restrict__ asrc, const float* __restrict__ adst,
                                 const int* __restrict__ off, const int* __restrict__ csr_src,
                                 const float* __restrict__ bias,
                                 _Float16* __restrict__ out,
                                 int N, int do_relu) {
    __shared__ float2 sm[4][64];
    int wslot = threadIdx.x >> 6;
    int wave = blockIdx.x * 4 + wslot;
    int lane = threadIdx.x & 63;
    if (wave >= N) return;
    int n = wave;
    int o0 = off[n], o1 = off[n + 1];
    float ad = adst[n];

    float denom = 0.f;
    float2 accA = make_float2(0.f, 0.f);
    float2 accB = make_float2(0.f, 0.f);

    for (int base = o0; base < o1; base += 64) {
        int cnt = o1 - base; if (cnt > 64) cnt = 64;
        float e = 0.f; int s = 0;
        if (lane < cnt) {
            s = csr_src[base + lane];
            e = __expf(lrelu(asrc[s] + ad));
        }
        float t = e;
#pragma unroll
        for (int o = 32; o > 0; o >>= 1) t += __shfl_xor(t, o);
        denom += t;
        sm[wslot][lane] = make_float2(__int_as_float(s), e);
        int j = 0;
        for (; j + 1 < cnt; j += 2) {
            float2 v0 = sm[wslot][j];
            float2 v1 = sm[wslot][j + 1];
            int s0 = __float_as_int(v0.x);
            int s1 = __float_as_int(v1.x);
            f16x2 h0 = *reinterpret_cast<const f16x2*>(&h[(size_t)s0 * HDIM + 2 * lane]);
            f16x2 h1 = *reinterpret_cast<const f16x2*>(&h[(size_t)s1 * HDIM + 2 * lane]);
            accA.x = fmaf(v0.y, (float)h0[0], accA.x);
            accA.y = fmaf(v0.y, (float)h0[1], accA.y);
            accB.x = fmaf(v1.y, (float)h1[0], accB.x);
            accB.y = fmaf(v1.y, (float)h1[1], accB.y);
        }
        if (j < cnt) {
            float2 v0 = sm[wslot][j];
            int s0 = __float_as_int(v0.x);
            f16x2 h0 = *reinterpret_cast<const f16x2*>(&h[(size_t)s0 * HDIM + 2 * lane]);
            accA.x = fmaf(v0.y, (float)h0[0], accA.x);
            accA.y = fmaf(v0.y, (float)h0[1], accA.y);
        }
    }

    float inv = 1.f / denom;
    float2 bi = *reinterpret_cast<const float2*>(&bias[2 * lane]);
    float r0 = (accA.x + accB.x) * inv + bi.x;
    float r1 = (accA.y + accB.y) * inv + bi.y;
    if (do_relu) { r0 = fmaxf(r0, 0.f); r1 = fmaxf(r1, 0.f); }
    f16x2 o;
    o[0] = (_Float16)r0;
    o[1] = (_Float16)r1;
    *reinterpret_cast<f16x2*>(&out[(size_t)n * HDIM + 2 * lane]) = o;
}

// ---------------- MLP head: out = sigmoid(Z[M,128] @ W[128,20] + b), fp16 Z ----------------
__global__ __launch_bounds__(256) void head_kernel(const _Float16* __restrict__ Z,
                                                   const float* __restrict__ W,
                                                   const float* __restrict__ b,
                                                   float* __restrict__ out, int N) {
    __shared__ float Ws[HDIM][NCLS];
    __shared__ float Zs[256][33];
    int tid = threadIdx.x;
    for (int i = tid; i < HDIM * NCLS; i += 256) Ws[i / NCLS][i % NCLS] = W[i];
    float acc[NCLS];
#pragma unroll
    for (int c = 0; c < NCLS; ++c) acc[c] = 0.f;
    int row = blockIdx.x * 256 + tid;
    for (int k0 = 0; k0 < HDIM; k0 += 32) {
        __syncthreads();
#pragma unroll
        for (int t = 0; t < 8; ++t) {
            int flat = tid * 4 + t * 1024;
            int r = flat >> 5, kk = flat & 31;
            int gr = blockIdx.x * 256 + r;
            if (gr < N) {
                f16x4 v = *reinterpret_cast<const f16x4*>(&Z[(size_t)gr * HDIM + k0 + kk]);
                Zs[r][kk] = (float)v[0]; Zs[r][kk + 1] = (float)v[1];
                Zs[r][kk + 2] = (float)v[2]; Zs[r][kk + 3] = (float)v[3];
            } else {
                Zs[r][kk] = 0.f; Zs[r][kk + 1] = 0.f; Zs[r][kk + 2] = 0.f; Zs[r][kk + 3] = 0.f;
            }
        }
        __syncthreads();
#pragma unroll
        for (int kk = 0; kk < 32; ++kk) {
            float a = Zs[tid][kk];
#pragma unroll
            for (int c = 0; c < NCLS; ++c) acc[c] = fmaf(a, Ws[k0 + kk][c], acc[c]);
        }
    }
    if (row < N) {
#pragma unroll
        for (int c = 0; c < NCLS; ++c) {
            float v = acc[c] + b[c];
            out[(size_t)row * NCLS + c] = 1.f / (1.f + expf(-v));
        }
    }
}

extern "C" void kernel_launch(void* const* d_in, const int* in_sizes, int n_in,
                              void* d_out, int out_size, void* d_ws, size_t ws_size,
                              hipStream_t stream) {
    const float* x      = (const float*)d_in[0];
    const int*   ei     = (const int*)d_in[1];
    const float* W1     = (const float*)d_in[2];
    const float* a_src1 = (const float*)d_in[3];
    const float* a_dst1 = (const float*)d_in[4];
    const float* b1     = (const float*)d_in[5];
    const float* W2     = (const float*)d_in[6];
    const float* a_src2 = (const float*)d_in[7];
    const float* a_dst2 = (const float*)d_in[8];
    const float* b2     = (const float*)d_in[9];
    const float* Wm1    = (const float*)d_in[10];
    const float* bm1    = (const float*)d_in[11];
    const float* Wm2    = (const float*)d_in[12];
    const float* bm2    = (const float*)d_in[13];

    int N = in_sizes[0] / F_IN;
    int E = in_sizes[1] / 2;
    int Etot = E + N;

    char* ws = (char*)d_ws;
    size_t pos = 0;
    auto alloc = [&](size_t bytes) -> void* {
        void* p = ws + pos;
        pos = (pos + bytes + 255) & ~(size_t)255;
        return p;
    };
    _Float16* h16 = (_Float16*)alloc((size_t)N * HDIM * 2);   // gemm out / gather in
    _Float16* f16 = (_Float16*)alloc((size_t)N * HDIM * 2);   // aggregate out / gemm A in
    float* as_buf = (float*)alloc((size_t)N * 4);
    float* ad_buf = (float*)alloc((size_t)N * 4);
    int*   deg    = (int*)alloc((size_t)N * 4);
    int*   offs   = (int*)alloc((size_t)(N + 1) * 4);
    int*   cursor = (int*)alloc((size_t)N * 4);
    int*   csr    = (int*)alloc((size_t)Etot * 4);
    int*   bsums  = (int*)alloc(256 * 4);
    unsigned short* p1 = (unsigned short*)alloc(65536 * 2);  // W1 packed (K=256)
    unsigned short* p2 = (unsigned short*)alloc(32768 * 2);  // W2 packed (K=128)
    unsigned short* p3 = (unsigned short*)alloc(32768 * 2);  // Wm1 packed (K=128)

    hipMemsetAsync(deg, 0, (size_t)N * 4, stream);
    hipMemsetAsync(cursor, 0, (size_t)N * 4, stream);

    int eb = (Etot + 255) / 256;
    int nb = (N + SCAN_CHUNK - 1) / SCAN_CHUNK;
    count_kernel<<<eb, 256, 0, stream>>>(ei, E, N, deg);
    scan_reduce_kernel<<<nb, 256, 0, stream>>>(deg, N, bsums);
    scan_bsums_kernel<<<1, 256, 0, stream>>>(bsums, nb, offs, N);
    scan_down_kernel<<<nb, 256, 0, stream>>>(deg, N, bsums, offs);
    scatter_kernel<<<eb, 256, 0, stream>>>(ei, E, N, offs, cursor, csr);

    pack_b_kernel<<<128, 64, 0, stream>>>(W1, W2, Wm1, p1, p2, p3);

    int gemm_blocks = (N + 63) / 64;
    int wave_blocks = (N + 3) / 4;

    // layer 1: h1 = x @ W1 (fp32 A inline-split); attention; relu
    gemm_mfma_kernel<0><<<gemm_blocks, 256, 0, stream>>>(x, p1, h16, N, F_IN, nullptr, 0);
    alphas_kernel<<<wave_blocks, 256, 0, stream>>>(h16, a_src1, a_dst1, as_buf, ad_buf, N);
    aggregate_kernel<<<wave_blocks, 256, 0, stream>>>(h16, as_buf, ad_buf, offs, csr, b1, f16, N, 1);

    // layer 2: h2 = f1 @ W2 (fp16 A); attention (no relu)
    gemm_mfma_kernel<1><<<gemm_blocks, 256, 0, stream>>>(f16, p2, h16, N, HDIM, nullptr, 0);
    alphas_kernel<<<wave_blocks, 256, 0, stream>>>(h16, a_src2, a_dst2, as_buf, ad_buf, N);
    aggregate_kernel<<<wave_blocks, 256, 0, stream>>>(h16, as_buf, ad_buf, offs, csr, b2, f16, N, 0);

    // MLP: z = relu(f2 @ Wm1 + bm1); out = sigmoid(z @ Wm2 + bm2)
    gemm_mfma_kernel<1><<<gemm_blocks, 256, 0, stream>>>(f16, p3, h16, N, HDIM, bm1, 1);
    head_kernel<<<(N + 255) / 256, 256, 0, stream>>>(h16, Wm2, bm2, (float*)d_out, N);
}

// Round 6
// 254.880 us; speedup vs baseline: 1.8279x; 1.0182x over previous
//
#include <hip/hip_runtime.h>
#include <math.h>

#define F_IN 256
#define HDIM 128
#define NCLS 20
#define NEG_SLOPE 0.2f
#define SCAN_CHUNK 1024

typedef float f32x4 __attribute__((ext_vector_type(4)));
typedef _Float16 f16x2 __attribute__((ext_vector_type(2)));
typedef _Float16 f16x4 __attribute__((ext_vector_type(4)));
typedef _Float16 f16x8 __attribute__((ext_vector_type(8)));

static __device__ __forceinline__ float lrelu(float x) { return x > 0.f ? x : NEG_SLOPE * x; }

// ---------------- CSR build ----------------
__global__ void count_kernel(const int* __restrict__ ei, int E, int N, int* __restrict__ deg) {
    int e = blockIdx.x * blockDim.x + threadIdx.x;
    int Etot = E + N;
    if (e >= Etot) return;
    int d = (e < E) ? ei[E + e] : (e - E);
    atomicAdd(&deg[d], 1);
}

__global__ __launch_bounds__(256) void scan_reduce_kernel(const int* __restrict__ deg, int n,
                                                          int* __restrict__ bsums) {
    int base = blockIdx.x * SCAN_CHUNK + threadIdx.x * 4;
    int s = 0;
    if (base + 3 < n) {
        int4 v = *reinterpret_cast<const int4*>(&deg[base]);
        s = v.x + v.y + v.z + v.w;
    } else {
#pragma unroll
        for (int j = 0; j < 4; ++j) if (base + j < n) s += deg[base + j];
    }
#pragma unroll
    for (int o = 32; o > 0; o >>= 1) s += __shfl_down(s, o);
    __shared__ int ws[4];
    int lane = threadIdx.x & 63, w = threadIdx.x >> 6;
    if (lane == 0) ws[w] = s;
    __syncthreads();
    if (threadIdx.x == 0) bsums[blockIdx.x] = ws[0] + ws[1] + ws[2] + ws[3];
}

__global__ __launch_bounds__(256) void scan_bsums_kernel(int* __restrict__ bsums, int nb,
                                                         int* __restrict__ off, int n) {
    __shared__ int sh[256];
    int tid = threadIdx.x;
    int v = (tid < nb) ? bsums[tid] : 0;
    sh[tid] = v;
    __syncthreads();
    for (int d = 1; d < 256; d <<= 1) {
        int t = (tid >= d) ? sh[tid - d] : 0;
        __syncthreads();
        sh[tid] += t;
        __syncthreads();
    }
    if (tid < nb) bsums[tid] = sh[tid] - v;
    if (tid == 255) off[n] = sh[255];
}

__global__ __launch_bounds__(256) void scan_down_kernel(const int* __restrict__ deg, int n,
                                                        const int* __restrict__ bpre,
                                                        int* __restrict__ off) {
    int base = blockIdx.x * SCAN_CHUNK + threadIdx.x * 4;
    int v0 = 0, v1 = 0, v2 = 0, v3 = 0;
    if (base + 3 < n) {
        int4 t = *reinterpret_cast<const int4*>(&deg[base]);
        v0 = t.x; v1 = t.y; v2 = t.z; v3 = t.w;
    } else {
        if (base + 0 < n) v0 = deg[base + 0];
        if (base + 1 < n) v1 = deg[base + 1];
        if (base + 2 < n) v2 = deg[base + 2];
        if (base + 3 < n) v3 = deg[base + 3];
    }
    int tsum = v0 + v1 + v2 + v3;
    int lane = threadIdx.x & 63, w = threadIdx.x >> 6;
    int inc = tsum;
#pragma unroll
    for (int o = 1; o < 64; o <<= 1) {
        int t = __shfl_up(inc, o);
        if (lane >= o) inc += t;
    }
    int texc = inc - tsum;
    __shared__ int wsum[4];
    if (lane == 63) wsum[w] = inc;
    __syncthreads();
    int wpre = 0;
    for (int i = 0; i < w; ++i) wpre += wsum[i];
    int p = bpre[blockIdx.x] + wpre + texc;
    if (base + 3 < n) {
        int4 o4;
        o4.x = p; o4.y = p + v0; o4.z = p + v0 + v1; o4.w = p + v0 + v1 + v2;
        *reinterpret_cast<int4*>(&off[base]) = o4;
    } else {
        int run = p;
        if (base + 0 < n) { off[base + 0] = run; run += v0; }
        if (base + 1 < n) { off[base + 1] = run; run += v1; }
        if (base + 2 < n) { off[base + 2] = run; run += v2; }
        if (base + 3 < n) { off[base + 3] = run; }
    }
}

__global__ void scatter_kernel(const int* __restrict__ ei, int E, int N,
                               const int* __restrict__ off, int* __restrict__ cursor,
                               int* __restrict__ csr_src) {
    int e = blockIdx.x * blockDim.x + threadIdx.x;
    int Etot = E + N;
    if (e >= Etot) return;
    int s, d;
    if (e < E) { s = ei[e]; d = ei[E + e]; } else { s = d = e - E; }
    int pos = off[d] + atomicAdd(&cursor[d], 1);
    csr_src[pos] = s;
}

// ---------------- pack weights into MFMA B-fragment order (fp16 hi/lo) ----------------
// layout: out[(((ks*8+cf)*2)*64 + lane)*8 + i]       = hi(B[ks*32+(lane>>4)*8+i][cf*16+(lane&15)])
//         out[(((ks*8+cf)*2)*64 + lane)*8 + 512 + i] = lo(...)
__global__ __launch_bounds__(64) void pack_b_kernel(const float* __restrict__ W1,
                                                    const float* __restrict__ W2,
                                                    const float* __restrict__ Wm1,
                                                    _Float16* __restrict__ p1,
                                                    _Float16* __restrict__ p2,
                                                    _Float16* __restrict__ p3) {
    int t = blockIdx.x;
    int lane = threadIdx.x;
    const float* B; _Float16* out; int r;
    if (t < 64)      { B = W1;  out = p1; r = t; }
    else if (t < 96) { B = W2;  out = p2; r = t - 64; }
    else             { B = Wm1; out = p3; r = t - 96; }
    int ks = r >> 3, cf = r & 7;
    int c  = cf * 16 + (lane & 15);
    int k0 = ks * 32 + (lane >> 4) * 8;
    _Float16 h8[8], l8[8];
#pragma unroll
    for (int i = 0; i < 8; ++i) {
        float v = B[(size_t)(k0 + i) * 128 + c];
        h8[i] = (_Float16)v;
        l8[i] = (_Float16)(v - (float)h8[i]);
    }
    size_t base = (((size_t)(ks * 8 + cf) * 2) * 64 + lane) * 8;
#pragma unroll
    for (int i = 0; i < 8; ++i) { out[base + i] = h8[i]; out[base + 512 + i] = l8[i]; }
}

// ---------------- MFMA GEMM: C[M,128](fp16) = A[M,K] @ Bpacked[K,128] ----------------
// AFMT: 0 = fp32 A (cvt to fp16 in regs), 1 = fp16 A (direct).
// B = fp16 hi+lo (2-term, near-fp32 weight precision). f16 MFMA, fp32 accum.
// No LDS/barriers. Block = 4 waves (2x2), wave = 32 rows x 64 cols.
// 2-deep ping-pong software pipeline over K-steps (ksteps always even).
template <int AFMT>
__global__ __launch_bounds__(256) void gemm_mfma_kernel(const void* __restrict__ Aptr,
                                                        const _Float16* __restrict__ Bp,
                                                        _Float16* __restrict__ C, int M, int K,
                                                        const float* __restrict__ bias, int act) {
    int tid = threadIdx.x;
    int lane = tid & 63;
    int wid = tid >> 6;
    int wr = wid >> 1, wc = wid & 1;
    int bm = blockIdx.x * 64;
    int l15 = lane & 15, l4 = lane >> 4;
    int row0 = bm + wr * 32 + l15;
    int koff = l4 * 8;

    f32x4 acc[2][4];
#pragma unroll
    for (int m = 0; m < 2; ++m)
#pragma unroll
        for (int j = 0; j < 4; ++j) acc[m][j] = (f32x4){0.f, 0.f, 0.f, 0.f};

    const f16x8 zf = {0, 0, 0, 0, 0, 0, 0, 0};

    auto loadA = [&](int ks, f16x8 a[2]) {
        int kbase = ks * 32 + koff;
#pragma unroll
        for (int m = 0; m < 2; ++m) {
            int rr = row0 + m * 16;
            if (rr < M) {
                if (AFMT == 0) {
                    const float* A = (const float*)Aptr;
                    float4 v0 = *reinterpret_cast<const float4*>(&A[(size_t)rr * K + kbase]);
                    float4 v1 = *reinterpret_cast<const float4*>(&A[(size_t)rr * K + kbase + 4]);
                    f16x8 t;
                    t[0] = (_Float16)v0.x; t[1] = (_Float16)v0.y;
                    t[2] = (_Float16)v0.z; t[3] = (_Float16)v0.w;
                    t[4] = (_Float16)v1.x; t[5] = (_Float16)v1.y;
                    t[6] = (_Float16)v1.z; t[7] = (_Float16)v1.w;
                    a[m] = t;
                } else {
                    const _Float16* A = (const _Float16*)Aptr;
                    a[m] = *reinterpret_cast<const f16x8*>(&A[(size_t)rr * K + kbase]);
                }
            } else a[m] = zf;
        }
    };
    auto loadB = [&](int ks, f16x8 bh[4], f16x8 bl[4]) {
#pragma unroll
        for (int j = 0; j < 4; ++j) {
            int cf = wc * 4 + j;
            const _Float16* bp = Bp + (((size_t)(ks * 8 + cf) * 2) * 64 + lane) * 8;
            bh[j] = *reinterpret_cast<const f16x8*>(bp);
            bl[j] = *reinterpret_cast<const f16x8*>(bp + 512);
        }
    };

    f16x8 a0[2], a1[2], bh0[4], bh1[4], bl0[4], bl1[4];
    int ksteps = K >> 5;   // 4 or 8, always even
    loadA(0, a0); loadB(0, bh0, bl0);
    for (int ks = 0; ks < ksteps; ks += 2) {
        loadA(ks + 1, a1); loadB(ks + 1, bh1, bl1);
#pragma unroll
        for (int j = 0; j < 4; ++j) {
            acc[0][j] = __builtin_amdgcn_mfma_f32_16x16x32_f16(a0[0], bh0[j], acc[0][j], 0, 0, 0);
            acc[1][j] = __builtin_amdgcn_mfma_f32_16x16x32_f16(a0[1], bh0[j], acc[1][j], 0, 0, 0);
            acc[0][j] = __builtin_amdgcn_mfma_f32_16x16x32_f16(a0[0], bl0[j], acc[0][j], 0, 0, 0);
            acc[1][j] = __builtin_amdgcn_mfma_f32_16x16x32_f16(a0[1], bl0[j], acc[1][j], 0, 0, 0);
        }
        if (ks + 2 < ksteps) { loadA(ks + 2, a0); loadB(ks + 2, bh0, bl0); }
#pragma unroll
        for (int j = 0; j < 4; ++j) {
            acc[0][j] = __builtin_amdgcn_mfma_f32_16x16x32_f16(a1[0], bh1[j], acc[0][j], 0, 0, 0);
            acc[1][j] = __builtin_amdgcn_mfma_f32_16x16x32_f16(a1[1], bh1[j], acc[1][j], 0, 0, 0);
            acc[0][j] = __builtin_amdgcn_mfma_f32_16x16x32_f16(a1[0], bl1[j], acc[0][j], 0, 0, 0);
            acc[1][j] = __builtin_amdgcn_mfma_f32_16x16x32_f16(a1[1], bl1[j], acc[1][j], 0, 0, 0);
        }
    }

#pragma unroll
    for (int j = 0; j < 4; ++j) {
        int col = wc * 64 + j * 16 + l15;
        float bi = bias ? bias[col] : 0.f;
#pragma unroll
        for (int m = 0; m < 2; ++m) {
            int rbase = bm + wr * 32 + m * 16 + l4 * 4;
#pragma unroll
            for (int reg = 0; reg < 4; ++reg) {
                int rr = rbase + reg;
                if (rr < M) {
                    float v = acc[m][j][reg] + bi;
                    if (act) v = fmaxf(v, 0.f);
                    C[(size_t)rr * 128 + col] = (_Float16)v;
                }
            }
        }
    }
}

// ---------------- per-node alpha dot products (fp16 h) ----------------
__global__ void alphas_kernel(const _Float16* __restrict__ h, const float* __restrict__ a_src,
                              const float* __restrict__ a_dst, float* __restrict__ as_out,
                              float* __restrict__ ad_out, int N) {
    int wave = (blockIdx.x * blockDim.x + threadIdx.x) >> 6;
    int lane = threadIdx.x & 63;
    if (wave >= N) return;
    f16x2 v  = *reinterpret_cast<const f16x2*>(&h[(size_t)wave * HDIM + 2 * lane]);
    float vx = (float)v[0], vy = (float)v[1];
    float2 as = *reinterpret_cast<const float2*>(&a_src[2 * lane]);
    float2 ad = *reinterpret_cast<const float2*>(&a_dst[2 * lane]);
    float s = vx * as.x + vy * as.y;
    float d = vx * ad.x + vy * ad.y;
#pragma unroll
    for (int o = 32; o > 0; o >>= 1) { s += __shfl_down(s, o); d += __shfl_down(d, o); }
    if (lane == 0) { as_out[wave] = s; ad_out[wave] = d; }
}

// ---------------- attention aggregation: one wave per dst node (fp16 gather) ----------------
__global__ __launch_bounds__(256) void aggregate_kernel(const _Float16* __restrict__ h,
                                 const float* __restrict__ asrc, const float* __restrict__ adst,
                                 const int* __restrict__ off, const int* __restrict__ csr_src,
                                 const float* __restrict__ bias,
                                 _Float16* __restrict__ out,
                                 int N, int do_relu) {
    __shared__ float2 sm[4][64];
    int wslot = threadIdx.x >> 6;
    int wave = blockIdx.x * 4 + wslot;
    int lane = threadIdx.x & 63;
    if (wave >= N) return;
    int n = wave;
    int o0 = off[n], o1 = off[n + 1];
    float ad = adst[n];

    float denom = 0.f;
    float2 accA = make_float2(0.f, 0.f);
    float2 accB = make_float2(0.f, 0.f);

    for (int base = o0; base < o1; base += 64) {
        int cnt = o1 - base; if (cnt > 64) cnt = 64;
        float e = 0.f; int s = 0;
        if (lane < cnt) {
            s = csr_src[base + lane];
            e = __expf(lrelu(asrc[s] + ad));
        }
        float t = e;
#pragma unroll
        for (int o = 32; o > 0; o >>= 1) t += __shfl_xor(t, o);
        denom += t;
        sm[wslot][lane] = make_float2(__int_as_float(s), e);
        int j = 0;
        for (; j + 1 < cnt; j += 2) {
            float2 v0 = sm[wslot][j];
            float2 v1 = sm[wslot][j + 1];
            int s0 = __float_as_int(v0.x);
            int s1 = __float_as_int(v1.x);
            f16x2 h0 = *reinterpret_cast<const f16x2*>(&h[(size_t)s0 * HDIM + 2 * lane]);
            f16x2 h1 = *reinterpret_cast<const f16x2*>(&h[(size_t)s1 * HDIM + 2 * lane]);
            accA.x = fmaf(v0.y, (float)h0[0], accA.x);
            accA.y = fmaf(v0.y, (float)h0[1], accA.y);
            accB.x = fmaf(v1.y, (float)h1[0], accB.x);
            accB.y = fmaf(v1.y, (float)h1[1], accB.y);
        }
        if (j < cnt) {
            float2 v0 = sm[wslot][j];
            int s0 = __float_as_int(v0.x);
            f16x2 h0 = *reinterpret_cast<const f16x2*>(&h[(size_t)s0 * HDIM + 2 * lane]);
            accA.x = fmaf(v0.y, (float)h0[0], accA.x);
            accA.y = fmaf(v0.y, (float)h0[1], accA.y);
        }
    }

    float inv = 1.f / denom;
    float2 bi = *reinterpret_cast<const float2*>(&bias[2 * lane]);
    float r0 = (accA.x + accB.x) * inv + bi.x;
    float r1 = (accA.y + accB.y) * inv + bi.y;
    if (do_relu) { r0 = fmaxf(r0, 0.f); r1 = fmaxf(r1, 0.f); }
    f16x2 o;
    o[0] = (_Float16)r0;
    o[1] = (_Float16)r1;
    *reinterpret_cast<f16x2*>(&out[(size_t)n * HDIM + 2 * lane]) = o;
}

// ---------------- MLP head: out = sigmoid(Z[M,128] @ W[128,20] + b), fp16 Z ----------------
__global__ __launch_bounds__(256) void head_kernel(const _Float16* __restrict__ Z,
                                                   const float* __restrict__ W,
                                                   const float* __restrict__ b,
                                                   float* __restrict__ out, int N) {
    __shared__ float Ws[HDIM][NCLS];
    __shared__ float Zs[256][33];
    int tid = threadIdx.x;
    for (int i = tid; i < HDIM * NCLS; i += 256) Ws[i / NCLS][i % NCLS] = W[i];
    float acc[NCLS];
#pragma unroll
    for (int c = 0; c < NCLS; ++c) acc[c] = 0.f;
    int row = blockIdx.x * 256 + tid;
    for (int k0 = 0; k0 < HDIM; k0 += 32) {
        __syncthreads();
#pragma unroll
        for (int t = 0; t < 8; ++t) {
            int flat = tid * 4 + t * 1024;
            int r = flat >> 5, kk = flat & 31;
            int gr = blockIdx.x * 256 + r;
            if (gr < N) {
                f16x4 v = *reinterpret_cast<const f16x4*>(&Z[(size_t)gr * HDIM + k0 + kk]);
                Zs[r][kk] = (float)v[0]; Zs[r][kk + 1] = (float)v[1];
                Zs[r][kk + 2] = (float)v[2]; Zs[r][kk + 3] = (float)v[3];
            } else {
                Zs[r][kk] = 0.f; Zs[r][kk + 1] = 0.f; Zs[r][kk + 2] = 0.f; Zs[r][kk + 3] = 0.f;
            }
        }
        __syncthreads();
#pragma unroll
        for (int kk = 0; kk < 32; ++kk) {
            float a = Zs[tid][kk];
#pragma unroll
            for (int c = 0; c < NCLS; ++c) acc[c] = fmaf(a, Ws[k0 + kk][c], acc[c]);
        }
    }
    if (row < N) {
#pragma unroll
        for (int c = 0; c < NCLS; ++c) {
            float v = acc[c] + b[c];
            out[(size_t)row * NCLS + c] = 1.f / (1.f + expf(-v));
        }
    }
}

extern "C" void kernel_launch(void* const* d_in, const int* in_sizes, int n_in,
                              void* d_out, int out_size, void* d_ws, size_t ws_size,
                              hipStream_t stream) {
    const float* x      = (const float*)d_in[0];
    const int*   ei     = (const int*)d_in[1];
    const float* W1     = (const float*)d_in[2];
    const float* a_src1 = (const float*)d_in[3];
    const float* a_dst1 = (const float*)d_in[4];
    const float* b1     = (const float*)d_in[5];
    const float* W2     = (const float*)d_in[6];
    const float* a_src2 = (const float*)d_in[7];
    const float* a_dst2 = (const float*)d_in[8];
    const float* b2     = (const float*)d_in[9];
    const float* Wm1    = (const float*)d_in[10];
    const float* bm1    = (const float*)d_in[11];
    const float* Wm2    = (const float*)d_in[12];
    const float* bm2    = (const float*)d_in[13];

    int N = in_sizes[0] / F_IN;
    int E = in_sizes[1] / 2;
    int Etot = E + N;

    char* ws = (char*)d_ws;
    size_t pos = 0;
    auto alloc = [&](size_t bytes) -> void* {
        void* p = ws + pos;
        pos = (pos + bytes + 255) & ~(size_t)255;
        return p;
    };
    _Float16* h16 = (_Float16*)alloc((size_t)N * HDIM * 2);   // gemm out / gather in
    _Float16* f16 = (_Float16*)alloc((size_t)N * HDIM * 2);   // aggregate out / gemm A in
    float* as_buf = (float*)alloc((size_t)N * 4);
    float* ad_buf = (float*)alloc((size_t)N * 4);
    int*   deg    = (int*)alloc((size_t)N * 4);
    int*   offs   = (int*)alloc((size_t)(N + 1) * 4);
    int*   cursor = (int*)alloc((size_t)N * 4);
    int*   csr    = (int*)alloc((size_t)Etot * 4);
    int*   bsums  = (int*)alloc(256 * 4);
    _Float16* p1 = (_Float16*)alloc(65536 * 2);  // W1 packed (K=256)
    _Float16* p2 = (_Float16*)alloc(32768 * 2);  // W2 packed (K=128)
    _Float16* p3 = (_Float16*)alloc(32768 * 2);  // Wm1 packed (K=128)

    hipMemsetAsync(deg, 0, (size_t)N * 4, stream);
    hipMemsetAsync(cursor, 0, (size_t)N * 4, stream);

    int eb = (Etot + 255) / 256;
    int nb = (N + SCAN_CHUNK - 1) / SCAN_CHUNK;
    count_kernel<<<eb, 256, 0, stream>>>(ei, E, N, deg);
    scan_reduce_kernel<<<nb, 256, 0, stream>>>(deg, N, bsums);
    scan_bsums_kernel<<<1, 256, 0, stream>>>(bsums, nb, offs, N);
    scan_down_kernel<<<nb, 256, 0, stream>>>(deg, N, bsums, offs);
    scatter_kernel<<<eb, 256, 0, stream>>>(ei, E, N, offs, cursor, csr);

    pack_b_kernel<<<128, 64, 0, stream>>>(W1, W2, Wm1, p1, p2, p3);

    int gemm_blocks = (N + 63) / 64;
    int wave_blocks = (N + 3) / 4;

    // layer 1: h1 = x @ W1 (fp32 A -> fp16 in regs); attention; relu
    gemm_mfma_kernel<0><<<gemm_blocks, 256, 0, stream>>>(x, p1, h16, N, F_IN, nullptr, 0);
    alphas_kernel<<<wave_blocks, 256, 0, stream>>>(h16, a_src1, a_dst1, as_buf, ad_buf, N);
    aggregate_kernel<<<wave_blocks, 256, 0, stream>>>(h16, as_buf, ad_buf, offs, csr, b1, f16, N, 1);

    // layer 2: h2 = f1 @ W2 (fp16 A); attention (no relu)
    gemm_mfma_kernel<1><<<gemm_blocks, 256, 0, stream>>>(f16, p2, h16, N, HDIM, nullptr, 0);
    alphas_kernel<<<wave_blocks, 256, 0, stream>>>(h16, a_src2, a_dst2, as_buf, ad_buf, N);
    aggregate_kernel<<<wave_blocks, 256, 0, stream>>>(h16, as_buf, ad_buf, offs, csr, b2, f16, N, 0);

    // MLP: z = relu(f2 @ Wm1 + bm1); out = sigmoid(z @ Wm2 + bm2)
    gemm_mfma_kernel<1><<<gemm_blocks, 256, 0, stream>>>(f16, p3, h16, N, HDIM, bm1, 1);
    head_kernel<<<(N + 255) / 256, 256, 0, stream>>>(h16, Wm2, bm2, (float*)d_out, N);
}